// Round 6
// baseline (6334.863 us; speedup 1.0000x reference)
//
#include <hip/hip_runtime.h>
#include <cstdint>
#include <cstddef>

#define HID 128
#define BSHIFT 7            // 128 nodes per bucket -> nbuck = 782 for N=100000
#define NSB 256             // scatter blocks (pass1/pass2 chunking)
#define MAXB 4096           // LDS sort capacity (avg bucket = 2046 edges)

// ROUND-18 NOTES (bit-exactness ledger + schedule ledger):
//  - CONTRACT (R13/R15/R16 fails): h, diff, tau must be BIT-IDENTICAL to the
//    R0 fmaf chains. No dtype compression, no MFMA, no reassociation.
//  - R14: agg needs >=~50% occupancy / small LDS. Keep agg blocks lean.
//  - R5 (PASS, neutral): role-split agg||gemm-p1 overlap works (~50% of p1
//    absorbed into agg's memory-bound time) but fp32-partial round-trip
//    (51MB W + 51MB R) + unoverlapped p2 gave it all back.
//  - THIS ROUND: full gemm in one block, acc stays in registers. Consumer
//    block spin-waits on a per-tile flag (producers: threadfence+atomicAdd;
//    consumer: atomic-load spin, then fence) = G16 device-scope pattern.
//    Interleave 16 producers : 1 consumer, consumer AFTER its producers in
//    dispatch order -> no deadlock, near-zero spin. gemm_p2 deleted.
//    gemm_in folded into bsort (role-split, union LDS) to overlap with sort.
//    All numeric code verbatim R5-passing.

// ======== deterministic two-pass bucket scatter (NO global atomics) ========
__global__ __launch_bounds__(256)
void ecount_kernel(const int* __restrict__ row, int* __restrict__ countsT,
                   int E, int nbuck,
                   const float* __restrict__ W_in, const float* __restrict__ Wd,
                   const float* __restrict__ W_ih, const float* __restrict__ W_hh,
                   float* __restrict__ WinT, float* __restrict__ WdT0,
                   float* __restrict__ WdT1, float* __restrict__ WihT,
                   float* __restrict__ WhhT) {
  // --- transpose prelude (180224 elements over 65536 threads) ---
  for (int i = blockIdx.x * 256 + threadIdx.x; i < 180224; i += NSB * 256) {
    int j = i;
    if (j < 16384) { int r = j >> 7, c = j & 127; WinT[c * 128 + r] = W_in[j]; continue; }
    j -= 16384;
    if (j < 32768) { int r = j >> 8, c = j & 255; WdT0[c * 128 + r] = Wd[j]; continue; }
    j -= 32768;
    if (j < 32768) { int r = j >> 8, c = j & 255; WdT1[c * 128 + r] = Wd[32768 + j]; continue; }
    j -= 32768;
    if (j < 49152) { int r = j >> 7, c = j & 127; WihT[c * 384 + r] = W_ih[j]; continue; }
    j -= 49152;
    { int r = j >> 7, c = j & 127; WhhT[c * 384 + r] = W_hh[j]; }
  }
  // --- bucket histogram ---
  __shared__ int lh[1024];
  int b = blockIdx.x;
  for (int i = threadIdx.x; i < nbuck; i += 256) lh[i] = 0;
  __syncthreads();
  int per = (E + NSB - 1) / NSB;
  int s = b * per, e = min(s + per, E);
  for (int i = s + (int)threadIdx.x; i < e; i += 256)
    atomicAdd(&lh[row[i] >> BSHIFT], 1);   // LDS atomic, shallow
  __syncthreads();
  for (int i = threadIdx.x; i < nbuck; i += 256) countsT[i * NSB + b] = lh[i];
}

__global__ __launch_bounds__(NSB)
void bprefix_kernel(int* __restrict__ countsT, int* __restrict__ btotal, int nbuck) {
  __shared__ int sd[NSB];
  int bk = blockIdx.x;
  int t = threadIdx.x;
  int v = countsT[bk * NSB + t];
  sd[t] = v;
  __syncthreads();
  for (int off = 1; off < NSB; off <<= 1) {
    int u = (t >= off) ? sd[t - off] : 0;
    __syncthreads();
    sd[t] += u;
    __syncthreads();
  }
  countsT[bk * NSB + t] = sd[t] - v;       // exclusive within bucket
  if (t == NSB - 1) btotal[bk] = sd[t];
}

__global__ __launch_bounds__(1024)
void bstart_kernel(const int* __restrict__ btotal, int* __restrict__ bstart,
                   int* __restrict__ offsets, int N, int nbuck) {
  __shared__ int sd[1024];
  int t = threadIdx.x;
  int v = (t < nbuck) ? btotal[t] : 0;
  sd[t] = v;
  __syncthreads();
  for (int off = 1; off < 1024; off <<= 1) {
    int u = (t >= off) ? sd[t - off] : 0;
    __syncthreads();
    sd[t] += u;
    __syncthreads();
  }
  if (t < nbuck) bstart[t] = sd[t] - v;
  if (t == nbuck - 1) { bstart[nbuck] = sd[t]; offsets[N] = sd[t]; }
}

__global__ __launch_bounds__(256)
void escatter_kernel(const int* __restrict__ row, const int* __restrict__ col,
                     const int* __restrict__ countsT, const int* __restrict__ bstart,
                     int2* __restrict__ ebuf, int E, int nbuck) {
  __shared__ int lcur[1024];
  int b = blockIdx.x;
  for (int i = threadIdx.x; i < nbuck; i += 256)
    lcur[i] = bstart[i] + countsT[i * NSB + b];
  __syncthreads();
  int per = (E + NSB - 1) / NSB;
  int s = b * per, e = min(s + per, E);
  for (int i = s + (int)threadIdx.x; i < e; i += 256) {
    int r = row[i], c = col[i];
    int pos = atomicAdd(&lcur[r >> BSHIFT], 1);
    ebuf[pos] = make_int2(r, c);
  }
}

// pass 3 + input GEMM (role-split): bid < nbuck -> per-bucket LDS counting
// sort by row -> CSR (offsets + csrcol), DETERMINISTIC (insertion-sorted by
// col). bid >= nbuck -> gemm_in tile (R5-verbatim): hA = relu(x@WinT+b_in).
// Independent outputs; LDS union'd (25KB); overlap sort (LDS-bound) with
// gemm (VALU-bound).
__global__ __launch_bounds__(256)
void bsort_gin_kernel(const int2* __restrict__ ebuf, const int* __restrict__ bstart,
                      int* __restrict__ offsets, int* __restrict__ csr_col,
                      int N, int nbuck,
                      const float* __restrict__ A, const float* __restrict__ BT,
                      const float* __restrict__ bias, float* __restrict__ C, int G) {
  __shared__ union {
    struct { int cnt[128]; int off[128]; int cur[128]; int lcol[MAXB]; } s;
    struct { float As[32][68]; float Bs[32][128]; } g;
  } sm;
  int bid = blockIdx.x;
  int tid = threadIdx.x;
  if (bid < nbuck) {
    int bk = bid;
    int s = bstart[bk], e = bstart[bk + 1];
    int m = e - s;
    if (tid < 128) sm.s.cnt[tid] = 0;
    __syncthreads();
    for (int i = s + tid; i < e; i += 256)
      atomicAdd(&sm.s.cnt[ebuf[i].x & 127], 1);
    __syncthreads();
    if (tid < 128) sm.s.off[tid] = sm.s.cnt[tid];
    __syncthreads();
    for (int d = 1; d < 128; d <<= 1) {
      int v = 0;
      if (tid < 128 && tid >= d) v = sm.s.off[tid - d];
      __syncthreads();
      if (tid < 128) sm.s.off[tid] += v;
      __syncthreads();
    }
    if (tid < 128) {
      sm.s.cur[tid] = sm.s.off[tid] - sm.s.cnt[tid];
      int node = (bk << BSHIFT) + tid;
      if (node < N) offsets[node] = s + sm.s.off[tid] - sm.s.cnt[tid];
    }
    __syncthreads();
    if (m <= MAXB) {
      for (int i = s + tid; i < e; i += 256) {
        int2 rc = ebuf[i];
        int pos = atomicAdd(&sm.s.cur[rc.x & 127], 1);
        sm.s.lcol[pos] = rc.y;
      }
      __syncthreads();
      if (tid < 128) {                               // per-node sort by col
        int b0 = sm.s.off[tid] - sm.s.cnt[tid], b1 = sm.s.off[tid];
        for (int i = b0 + 1; i < b1; ++i) {
          int key = sm.s.lcol[i];
          int j = i - 1;
          while (j >= b0 && sm.s.lcol[j] > key) { sm.s.lcol[j + 1] = sm.s.lcol[j]; --j; }
          sm.s.lcol[j + 1] = key;
        }
      }
      __syncthreads();
      for (int i = tid; i < m; i += 256) csr_col[s + i] = sm.s.lcol[i];
    } else {
      for (int i = s + tid; i < e; i += 256) {
        int2 rc = ebuf[i];
        int pos = atomicAdd(&sm.s.cur[rc.x & 127], 1);
        csr_col[s + pos] = rc.y;
      }
    }
    return;
  }
  // ---------------- gemm_in tile (R5-verbatim math) ----------------
  int tile = bid - nbuck;
  if (tile >= G) return;
  int tx = tid & 31;
  int ty = tid >> 5;
  int i0 = tile * 64;
  int M = N;
  float acc[8][4] = {};
  for (int kc = 0; kc < 4; ++kc) {
    int ksrc = kc * 32;
    #pragma unroll
    for (int q = 0; q < 2; ++q) {
      int f = q * 256 + tid;
      int i = f >> 3;
      int kq = (f & 7) << 2;
      int ig = i0 + i; if (ig >= M) ig = M - 1;
      float4 v = *(const float4*)(A + (size_t)ig * HID + ksrc + kq);
      sm.g.As[kq + 0][i] = v.x; sm.g.As[kq + 1][i] = v.y;
      sm.g.As[kq + 2][i] = v.z; sm.g.As[kq + 3][i] = v.w;
    }
    #pragma unroll
    for (int q = 0; q < 4; ++q) {
      int f = q * 256 + tid;
      int k = f >> 5; int c4 = (f & 31) << 2;
      *(float4*)&sm.g.Bs[k][c4] = *(const float4*)(BT + (size_t)(ksrc + k) * HID + c4);
    }
    __syncthreads();
    #pragma unroll
    for (int k = 0; k < 32; ++k) {
      float a[8];
      const float4* ap = (const float4*)&sm.g.As[k][ty * 8];
      float4 a0 = ap[0], a1 = ap[1];
      a[0]=a0.x; a[1]=a0.y; a[2]=a0.z; a[3]=a0.w;
      a[4]=a1.x; a[5]=a1.y; a[6]=a1.z; a[7]=a1.w;
      float4 b4 = *(const float4*)&sm.g.Bs[k][tx * 4];
      #pragma unroll
      for (int r = 0; r < 8; ++r) {
        acc[r][0] = fmaf(a[r], b4.x, acc[r][0]);
        acc[r][1] = fmaf(a[r], b4.y, acc[r][1]);
        acc[r][2] = fmaf(a[r], b4.z, acc[r][2]);
        acc[r][3] = fmaf(a[r], b4.w, acc[r][3]);
      }
    }
    __syncthreads();
  }
  float4 bias4 = *(const float4*)(bias + tx * 4);
  #pragma unroll
  for (int r = 0; r < 8; ++r) {
    int row = i0 + ty * 8 + r;
    if (row >= M) continue;
    float4 v4 = make_float4(fmaxf(acc[r][0] + bias4.x, 0.f),
                            fmaxf(acc[r][1] + bias4.y, 0.f),
                            fmaxf(acc[r][2] + bias4.z, 0.f),
                            fmaxf(acc[r][3] + bias4.w, 0.f));
    *(float4*)(C + (size_t)row * HID + tx * 4) = v4;
  }
}

// ---------------- per-node aggregate body (R0-VERBATIM math; frozen) --------
__device__ __forceinline__ void agg_one_node(const float* __restrict__ h,
                                             const int* __restrict__ offsets,
                                             const int* __restrict__ csr_col,
                                             float* __restrict__ diff, int node) {
  int lane = threadIdx.x & 63;
  int start = offsets[node], end = offsets[node + 1];
  int deg = end - start;
  const float2* hrow = (const float2*)(h + (size_t)node * HID);
  float2 hv = hrow[lane];
  float a0 = 0.f, a1 = 0.f;

  int batch = min(deg, 64);
  int myc = (lane < batch) ? csr_col[start + lane] : 0;
  int j = 0;
  for (; j + 16 <= batch; j += 16) {
    const float2* p0 = (const float2*)(h + (size_t)__shfl(myc, j + 0) * HID);
    const float2* p1 = (const float2*)(h + (size_t)__shfl(myc, j + 1) * HID);
    const float2* p2 = (const float2*)(h + (size_t)__shfl(myc, j + 2) * HID);
    const float2* p3 = (const float2*)(h + (size_t)__shfl(myc, j + 3) * HID);
    const float2* p4 = (const float2*)(h + (size_t)__shfl(myc, j + 4) * HID);
    const float2* p5 = (const float2*)(h + (size_t)__shfl(myc, j + 5) * HID);
    const float2* p6 = (const float2*)(h + (size_t)__shfl(myc, j + 6) * HID);
    const float2* p7 = (const float2*)(h + (size_t)__shfl(myc, j + 7) * HID);
    const float2* q0 = (const float2*)(h + (size_t)__shfl(myc, j + 8) * HID);
    const float2* q1 = (const float2*)(h + (size_t)__shfl(myc, j + 9) * HID);
    const float2* q2 = (const float2*)(h + (size_t)__shfl(myc, j + 10) * HID);
    const float2* q3 = (const float2*)(h + (size_t)__shfl(myc, j + 11) * HID);
    const float2* q4 = (const float2*)(h + (size_t)__shfl(myc, j + 12) * HID);
    const float2* q5 = (const float2*)(h + (size_t)__shfl(myc, j + 13) * HID);
    const float2* q6 = (const float2*)(h + (size_t)__shfl(myc, j + 14) * HID);
    const float2* q7 = (const float2*)(h + (size_t)__shfl(myc, j + 15) * HID);
    float2 x0 = p0[lane], x1 = p1[lane], x2 = p2[lane], x3 = p3[lane];
    float2 x4 = p4[lane], x5 = p5[lane], x6 = p6[lane], x7 = p7[lane];
    float2 y0 = q0[lane], y1 = q1[lane], y2 = q2[lane], y3 = q3[lane];
    float2 y4 = q4[lane], y5 = q5[lane], y6 = q6[lane], y7 = q7[lane];
    a0 += fabsf(hv.x - x0.x) + fabsf(hv.x - x1.x) + fabsf(hv.x - x2.x) + fabsf(hv.x - x3.x)
        + fabsf(hv.x - x4.x) + fabsf(hv.x - x5.x) + fabsf(hv.x - x6.x) + fabsf(hv.x - x7.x);
    a1 += fabsf(hv.y - x0.y) + fabsf(hv.y - x1.y) + fabsf(hv.y - x2.y) + fabsf(hv.y - x3.y)
        + fabsf(hv.y - x4.y) + fabsf(hv.y - x5.y) + fabsf(hv.y - x6.y) + fabsf(hv.y - x7.y);
    a0 += fabsf(hv.x - y0.x) + fabsf(hv.x - y1.x) + fabsf(hv.x - y2.x) + fabsf(hv.x - y3.x)
        + fabsf(hv.x - y4.x) + fabsf(hv.x - y5.x) + fabsf(hv.x - y6.x) + fabsf(hv.x - y7.x);
    a1 += fabsf(hv.y - y0.y) + fabsf(hv.y - y1.y) + fabsf(hv.y - y2.y) + fabsf(hv.y - y3.y)
        + fabsf(hv.y - y4.y) + fabsf(hv.y - y5.y) + fabsf(hv.y - y6.y) + fabsf(hv.y - y7.y);
  }
  for (; j + 8 <= batch; j += 8) {
    const float2* p0 = (const float2*)(h + (size_t)__shfl(myc, j + 0) * HID);
    const float2* p1 = (const float2*)(h + (size_t)__shfl(myc, j + 1) * HID);
    const float2* p2 = (const float2*)(h + (size_t)__shfl(myc, j + 2) * HID);
    const float2* p3 = (const float2*)(h + (size_t)__shfl(myc, j + 3) * HID);
    const float2* p4 = (const float2*)(h + (size_t)__shfl(myc, j + 4) * HID);
    const float2* p5 = (const float2*)(h + (size_t)__shfl(myc, j + 5) * HID);
    const float2* p6 = (const float2*)(h + (size_t)__shfl(myc, j + 6) * HID);
    const float2* p7 = (const float2*)(h + (size_t)__shfl(myc, j + 7) * HID);
    float2 x0 = p0[lane], x1 = p1[lane], x2 = p2[lane], x3 = p3[lane];
    float2 x4 = p4[lane], x5 = p5[lane], x6 = p6[lane], x7 = p7[lane];
    a0 += fabsf(hv.x - x0.x) + fabsf(hv.x - x1.x) + fabsf(hv.x - x2.x) + fabsf(hv.x - x3.x)
        + fabsf(hv.x - x4.x) + fabsf(hv.x - x5.x) + fabsf(hv.x - x6.x) + fabsf(hv.x - x7.x);
    a1 += fabsf(hv.y - x0.y) + fabsf(hv.y - x1.y) + fabsf(hv.y - x2.y) + fabsf(hv.y - x3.y)
        + fabsf(hv.y - x4.y) + fabsf(hv.y - x5.y) + fabsf(hv.y - x6.y) + fabsf(hv.y - x7.y);
  }
  for (; j < batch; ++j) {
    const float2* p = (const float2*)(h + (size_t)__shfl(myc, j) * HID);
    float2 x = p[lane];
    a0 += fabsf(hv.x - x.x);
    a1 += fabsf(hv.y - x.y);
  }
  for (int e = start + 64; e < end; ++e) {
    const float2* p = (const float2*)(h + (size_t)csr_col[e] * HID);
    float2 x = p[lane];
    a0 += fabsf(hv.x - x.x);
    a1 += fabsf(hv.y - x.y);
  }
  *(float2*)(diff + (size_t)node * HID + 2 * lane) = make_float2(a0, a1);
}

// ===== FUSED layer kernel: agg producers + full-GEMM consumers ==============
// Interleave 17: bids r=0..15 -> agg groups (4 nodes each) for tile t=bid/17;
// r=16 -> consumer gemm for tile t (AFTER its producers in dispatch order ->
// no deadlock; spin ~0 since producers are co-resident/ahead).
// Producer publish: stores -> __threadfence() -> __syncthreads() -> tid0
// atomicAdd(flags[t],1). Consumer: p1 chunks 0-3 over h (no dependency),
// spin until flags[t]==target, __threadfence(), chunks 4-7 over diff, then
// R5-verbatim epilogue (bias/relu/C-store, tau grouping, OUT head).
// acc never leaves registers -> chain == R0 bits. LDS 25KB, lb(256,4).
template<bool OUT>
__global__ __launch_bounds__(256, 4)
void fused_layer_kernel(const float* __restrict__ h, const int* __restrict__ offsets,
                        const int* __restrict__ csr_col, float* __restrict__ diff,
                        const float* __restrict__ BT, const float* __restrict__ bias,
                        float* __restrict__ C, int M, int nagg, int G,
                        int* __restrict__ flags,
                        const float* __restrict__ Wt, const float* __restrict__ bt,
                        float* __restrict__ tau_out, int* __restrict__ mlist,
                        int* __restrict__ mcount,
                        const float* __restrict__ Wo, const float* __restrict__ bo,
                        float* __restrict__ outp) {
  __shared__ float As[32][68];
  __shared__ float Bs[32][128];
  __shared__ float taured[64];
  int bid = blockIdx.x;
  int tid = threadIdx.x;
  int t = bid / 17, r17 = bid % 17;

  if (r17 < 16) {
    // ---------------- producer: one agg group (4 nodes, one per wave) -------
    int aidx = t * 16 + r17;
    if (aidx >= nagg) return;
    int wave = tid >> 6;
    int node = aidx * 4 + wave;
    if (node < M) agg_one_node(h, offsets, csr_col, diff, node);
    __threadfence();              // release diff stores to device scope
    __syncthreads();              // all waves' fences done
    if (tid == 0) atomicAdd(&flags[t], 1);
    return;
  }

  // ---------------- consumer: full gemm for tile t ----------------
  int tx = tid & 31;
  int ty = tid >> 5;
  int i0 = t * 64;
  float acc[8][4] = {};
  // p1: chunks 0..3 over h (independent of diff)
  for (int kc = 0; kc < 4; ++kc) {
    int ksrc = kc * 32;
    #pragma unroll
    for (int q = 0; q < 2; ++q) {
      int f = q * 256 + tid;
      int i = f >> 3;
      int kq = (f & 7) << 2;
      int ig = i0 + i; if (ig >= M) ig = M - 1;
      float4 v = *(const float4*)(h + (size_t)ig * HID + ksrc + kq);
      As[kq + 0][i] = v.x; As[kq + 1][i] = v.y;
      As[kq + 2][i] = v.z; As[kq + 3][i] = v.w;
    }
    #pragma unroll
    for (int q = 0; q < 4; ++q) {
      int f = q * 256 + tid;
      int k = f >> 5; int c4 = (f & 31) << 2;
      *(float4*)&Bs[k][c4] = *(const float4*)(BT + (size_t)(ksrc + k) * HID + c4);
    }
    __syncthreads();
    #pragma unroll
    for (int k = 0; k < 32; ++k) {
      float a[8];
      const float4* ap = (const float4*)&As[k][ty * 8];
      float4 a0 = ap[0], a1 = ap[1];
      a[0]=a0.x; a[1]=a0.y; a[2]=a0.z; a[3]=a0.w;
      a[4]=a1.x; a[5]=a1.y; a[6]=a1.z; a[7]=a1.w;
      float4 b4 = *(const float4*)&Bs[k][tx * 4];
      #pragma unroll
      for (int r = 0; r < 8; ++r) {
        acc[r][0] = fmaf(a[r], b4.x, acc[r][0]);
        acc[r][1] = fmaf(a[r], b4.y, acc[r][1]);
        acc[r][2] = fmaf(a[r], b4.z, acc[r][2]);
        acc[r][3] = fmaf(a[r], b4.w, acc[r][3]);
      }
    }
    __syncthreads();
  }
  // wait for this tile's diff rows (producers are earlier blocks)
  if (tid == 0) {
    int target = min(16, nagg - t * 16);
    while (__hip_atomic_load(&flags[t], __ATOMIC_RELAXED,
                             __HIP_MEMORY_SCOPE_AGENT) < target) {
      __builtin_amdgcn_s_sleep(8);
    }
  }
  __syncthreads();
  __threadfence();                // acquire: order diff loads after flag
  // p2: chunks 4..7 over diff (same fmaf chain, acc in registers)
  for (int kc = 4; kc < 8; ++kc) {
    int ksrc = (kc & 3) * 32;
    int kglob = kc * 32;
    #pragma unroll
    for (int q = 0; q < 2; ++q) {
      int f = q * 256 + tid;
      int i = f >> 3;
      int kq = (f & 7) << 2;
      int ig = i0 + i; if (ig >= M) ig = M - 1;
      float4 v = *(const float4*)(diff + (size_t)ig * HID + ksrc + kq);
      As[kq + 0][i] = v.x; As[kq + 1][i] = v.y;
      As[kq + 2][i] = v.z; As[kq + 3][i] = v.w;
    }
    #pragma unroll
    for (int q = 0; q < 4; ++q) {
      int f = q * 256 + tid;
      int k = f >> 5; int c4 = (f & 31) << 2;
      *(float4*)&Bs[k][c4] = *(const float4*)(BT + (size_t)(kglob + k) * HID + c4);
    }
    __syncthreads();
    #pragma unroll
    for (int k = 0; k < 32; ++k) {
      float a[8];
      const float4* ap = (const float4*)&As[k][ty * 8];
      float4 a0 = ap[0], a1 = ap[1];
      a[0]=a0.x; a[1]=a0.y; a[2]=a0.z; a[3]=a0.w;
      a[4]=a1.x; a[5]=a1.y; a[6]=a1.z; a[7]=a1.w;
      float4 b4 = *(const float4*)&Bs[k][tx * 4];
      #pragma unroll
      for (int r = 0; r < 8; ++r) {
        acc[r][0] = fmaf(a[r], b4.x, acc[r][0]);
        acc[r][1] = fmaf(a[r], b4.y, acc[r][1]);
        acc[r][2] = fmaf(a[r], b4.z, acc[r][2]);
        acc[r][3] = fmaf(a[r], b4.w, acc[r][3]);
      }
    }
    __syncthreads();
  }

  // ---- R5-verbatim epilogue ----
  float4 bias4 = *(const float4*)(bias + tx * 4);
  float bias_r[4] = {bias4.x, bias4.y, bias4.z, bias4.w};
  float4 w4 = *(const float4*)(Wt + tx * 4);
  float wt_r[4] = {w4.x, w4.y, w4.z, w4.w};
  float4 wo0 = make_float4(0.f, 0.f, 0.f, 0.f);
  float4 wo1 = make_float4(0.f, 0.f, 0.f, 0.f);
  if constexpr (OUT) {
    wo0 = *(const float4*)(Wo + tx * 4);
    wo1 = *(const float4*)(Wo + 128 + tx * 4);
  }
  #pragma unroll
  for (int r = 0; r < 8; ++r) {
    int row = i0 + ty * 8 + r;
    bool ok = row < M;
    float v0 = fmaxf(acc[r][0] + bias_r[0], 0.f);
    float v1 = fmaxf(acc[r][1] + bias_r[1], 0.f);
    float v2 = fmaxf(acc[r][2] + bias_r[2], 0.f);
    float v3 = fmaxf(acc[r][3] + bias_r[3], 0.f);
    if (ok) {
      float4 v4 = make_float4(v0, v1, v2, v3);
      *(float4*)(C + (size_t)row * HID + tx * 4) = v4;    // dwordx4 store
    }
    if constexpr (OUT) {
      float o0 = v0 * wo0.x + v1 * wo0.y + v2 * wo0.z + v3 * wo0.w;
      float o1 = v0 * wo1.x + v1 * wo1.y + v2 * wo1.z + v3 * wo1.w;
      o0 += __shfl_down(o0, 16, 32); o1 += __shfl_down(o1, 16, 32);
      o0 += __shfl_down(o0, 8, 32);  o1 += __shfl_down(o1, 8, 32);
      o0 += __shfl_down(o0, 4, 32);  o1 += __shfl_down(o1, 4, 32);
      o0 += __shfl_down(o0, 2, 32);  o1 += __shfl_down(o1, 2, 32);
      o0 += __shfl_down(o0, 1, 32);  o1 += __shfl_down(o1, 1, 32);
      if (tx == 0 && ok) {
        outp[(size_t)row * 2 + 0] = o0 + bo[0];
        outp[(size_t)row * 2 + 1] = o1 + bo[1];
      }
    }
    {
      float pf = v0 * wt_r[0];
      pf = fmaf(v1, wt_r[1], pf);
      pf = fmaf(v2, wt_r[2], pf);
      pf = fmaf(v3, wt_r[3], pf);
      pf += __shfl_down(pf, 16, 32);
      pf += __shfl_down(pf, 8, 32);
      pf += __shfl_down(pf, 4, 32);
      pf += __shfl_down(pf, 2, 32);
      pf += __shfl_down(pf, 1, 32);
      if (tx == 0) taured[ty * 8 + r] = pf;
    }
  }
  __syncthreads();
  if (tid < 64) {
    int row = i0 + tid;
    if (row < M) {
      float pre = taured[tid] + bt[0];
      float tau = (pre > 20.f) ? pre : log1pf(expf(pre));
      tau_out[row] = tau;
      // np semantics: floor(1/tau).astype(int32) overflows to INT_MIN for
      // 1/tau >= 2^31 -> n_updates <= 0 -> NOT masked even though tau<0.005.
      if (tau < 0.005f && (1.0f / tau) < 2147483648.0f) {
        int pos = atomicAdd(mcount, 1);
        mlist[pos] = row;
      }
    }
  }
}

// ---------------- masked GRU, 32 nodes / block (512 threads) ----------------
// template<LAST>: LAST recomputes the fused out rows it overwrites (R5-proven).
template<bool LAST>
__global__ __launch_bounds__(512)
void gru_kernel(const float* __restrict__ diff, float* __restrict__ h,
                const int* __restrict__ list, const int* __restrict__ count,
                const float* __restrict__ WihT, const float* __restrict__ WhhT,
                const float* __restrict__ b_ih, const float* __restrict__ b_hh,
                const float* __restrict__ Wo, const float* __restrict__ bo,
                float* __restrict__ outp) {
  int cnt = *count;
  int base = blockIdx.x * 32;
  if (base >= cnt) return;
  __shared__ float dl[32][HID];
  __shared__ float hl[32][HID];
  __shared__ int ids[32];
  __shared__ float osum[32][2][2];   // [row][wave-half][out-dim] (LAST only)
  int tid = threadIdx.x;
  if (tid < 32) ids[tid] = (base + tid < cnt) ? list[base + tid] : -1;
  __syncthreads();
  #pragma unroll
  for (int q = 0; q < 8; ++q) {
    int f = q * 512 + tid;
    int r = f >> 7, c = f & 127;
    int id = ids[r];
    int src = (id >= 0) ? id : 0;
    dl[r][c] = diff[(size_t)src * HID + c];
    hl[r][c] = h[(size_t)src * HID + c];
  }
  __syncthreads();
  int tx = tid & 127, ty = tid >> 7;   // ty in 0..3 -> rows ty*8..ty*8+7
  float air[8] = {}, aiz[8] = {}, ain[8] = {}, ahr[8] = {}, ahz[8] = {}, ahn[8] = {};
  for (int k = 0; k < HID; ++k) {
    float wir = WihT[k * 384 + tx];
    float wiz = WihT[k * 384 + 128 + tx];
    float win = WihT[k * 384 + 256 + tx];
    float whr = WhhT[k * 384 + tx];
    float whz = WhhT[k * 384 + 128 + tx];
    float whn = WhhT[k * 384 + 256 + tx];
    #pragma unroll
    for (int r = 0; r < 8; ++r) {
      float dk = dl[ty * 8 + r][k];
      float hk = hl[ty * 8 + r][k];
      air[r] = fmaf(dk, wir, air[r]);
      aiz[r] = fmaf(dk, wiz, aiz[r]);
      ain[r] = fmaf(dk, win, ain[r]);
      ahr[r] = fmaf(hk, whr, ahr[r]);
      ahz[r] = fmaf(hk, whz, ahz[r]);
      ahn[r] = fmaf(hk, whn, ahn[r]);
    }
  }
  float bir = b_ih[tx], biz = b_ih[128 + tx], bin = b_ih[256 + tx];
  float bhr = b_hh[tx], bhz = b_hh[128 + tx], bhn = b_hh[256 + tx];
  float wol0 = 0.f, wol1 = 0.f;
  if constexpr (LAST) { wol0 = Wo[tx]; wol1 = Wo[128 + tx]; }
  #pragma unroll
  for (int r = 0; r < 8; ++r) {
    int id = ids[ty * 8 + r];
    // compute unconditionally (id<0 rows use row-0 staged data) so the LAST
    // shfl reduce stays non-divergent; only stores are guarded.
    float rg = 1.f / (1.f + expf(-((air[r] + bir) + (ahr[r] + bhr))));
    float z  = 1.f / (1.f + expf(-((aiz[r] + biz) + (ahz[r] + bhz))));
    float n  = tanhf((ain[r] + bin) + rg * (ahn[r] + bhn));
    float hv = hl[ty * 8 + r][tx];
    float hnew = (1.f - z) * n + z * hv;
    if (id >= 0) h[(size_t)id * HID + tx] = hnew;
    if constexpr (LAST) {
      float p0 = hnew * wol0;
      float p1 = hnew * wol1;
      // tx spans 2 waves (0..63 = first, 64..127 = second); 64-lane reduce each
      p0 += __shfl_down(p0, 32, 64); p1 += __shfl_down(p1, 32, 64);
      p0 += __shfl_down(p0, 16, 64); p1 += __shfl_down(p1, 16, 64);
      p0 += __shfl_down(p0, 8, 64);  p1 += __shfl_down(p1, 8, 64);
      p0 += __shfl_down(p0, 4, 64);  p1 += __shfl_down(p1, 4, 64);
      p0 += __shfl_down(p0, 2, 64);  p1 += __shfl_down(p1, 2, 64);
      p0 += __shfl_down(p0, 1, 64);  p1 += __shfl_down(p1, 1, 64);
      if ((tx & 63) == 0) {
        osum[ty * 8 + r][tx >> 6][0] = p0;
        osum[ty * 8 + r][tx >> 6][1] = p1;
      }
    }
  }
  if constexpr (LAST) {
    __syncthreads();
    if (tid < 32) {
      int id = ids[tid];
      if (id >= 0) {
        outp[(size_t)id * 2 + 0] = osum[tid][0][0] + osum[tid][1][0] + bo[0];
        outp[(size_t)id * 2 + 1] = osum[tid][0][1] + osum[tid][1][1] + bo[1];
      }
    }
  }
}

extern "C" void kernel_launch(void* const* d_in, const int* in_sizes, int n_in,
                              void* d_out, int out_size, void* d_ws, size_t ws_size,
                              hipStream_t stream) {
  const float* x    = (const float*)d_in[0];
  const int*   ei   = (const int*)d_in[1];
  const float* W_in = (const float*)d_in[2];
  const float* b_in = (const float*)d_in[3];
  const float* Wd   = (const float*)d_in[4];
  const float* bd   = (const float*)d_in[5];
  const float* Wt   = (const float*)d_in[6];
  const float* bt   = (const float*)d_in[7];
  const float* W_ih = (const float*)d_in[8];
  const float* W_hh = (const float*)d_in[9];
  const float* b_ih = (const float*)d_in[10];
  const float* b_hh = (const float*)d_in[11];
  const float* Wo   = (const float*)d_in[12];
  const float* bo   = (const float*)d_in[13];

  const int N = in_sizes[0] / HID;      // 100000
  const int E = in_sizes[1] / 2;        // 1600000
  const int* rowp = ei;
  const int* colp = ei + E;
  const int nbuck = (N + (1 << BSHIFT) - 1) >> BSHIFT;   // 782 (<=1024)

  // workspace carve-up (256B aligned)
  char* p = (char*)d_ws;
  auto alloc = [&](size_t bytes) { void* r = (void*)p; p += (bytes + 255) & ~(size_t)255; return r; };
  float* hA     = (float*)alloc((size_t)N * HID * 4);
  float* hB     = (float*)alloc((size_t)N * HID * 4);
  float* diff   = (float*)alloc((size_t)N * HID * 4);
  float* WinT   = (float*)alloc(128 * 128 * 4);
  float* WdT0   = (float*)alloc(256 * 128 * 4);
  float* WdT1   = (float*)alloc(256 * 128 * 4);
  float* WihT   = (float*)alloc(128 * 384 * 4);
  float* WhhT   = (float*)alloc(128 * 384 * 4);
  float* tau0   = (float*)alloc((size_t)N * 4);
  int*   list   = (int*)alloc((size_t)N * 4);
  int*   zbase  = (int*)alloc(20480);    // count[2] + flags0[2048] + flags1[2048]
  int*   count  = zbase;
  int*   flags0 = zbase + 64;
  int*   flags1 = zbase + 64 + 2048;
  int*   countsT= (int*)alloc((size_t)1024 * NSB * 4);
  int*   btotal = (int*)alloc(1024 * 4);
  int*   bstart = (int*)alloc(1028 * 4);
  int*   offs   = (int*)alloc(((size_t)N + 1) * 4);
  int*   csrcol = (int*)alloc((size_t)E * 4);
  int2*  ebuf   = (int2*)alloc((size_t)E * 8);

  float* out_ptr = (float*)d_out;            // [N,2] flat
  float* tau_out = (float*)d_out + (size_t)N * 2;  // [N]

  // zero mask counters + both layers' tile flags (ws poisoned every launch)
  hipMemsetAsync(zbase, 0, 20480, stream);

  // CSR build, no global atomics, DETERMINISTIC csrcol (reused by both layers)
  ecount_kernel<<<NSB, 256, 0, stream>>>(rowp, countsT, E, nbuck,
                                         W_in, Wd, W_ih, W_hh,
                                         WinT, WdT0, WdT1, WihT, WhhT);
  bprefix_kernel<<<nbuck, NSB, 0, stream>>>(countsT, btotal, nbuck);
  bstart_kernel<<<1, 1024, 0, stream>>>(btotal, bstart, offs, N, nbuck);
  escatter_kernel<<<NSB, 256, 0, stream>>>(rowp, colp, countsT, bstart, ebuf, E, nbuck);

  const int G = (N + 63) / 64;                 // 1563 gemm tiles
  const int nagg = (N + 3) / 4;                // 25000 agg groups
  const int gru_blocks = (N + 31) / 32;

  // bsort + input-layer gemm (role-split, overlapped)
  bsort_gin_kernel<<<nbuck + G, 256, 0, stream>>>(
      ebuf, bstart, offs, csrcol, N, nbuck, x, WinT, b_in, hA, G);

  // ---- layer 0 ---- (agg producers + full-gemm consumers, flag-synced)
  fused_layer_kernel<false><<<17 * G, 256, 0, stream>>>(
      hA, offs, csrcol, diff, WdT0, bd, hB, N, nagg, G, flags0,
      Wt, bt, tau0, list, count, nullptr, nullptr, nullptr);
  gru_kernel<false><<<gru_blocks, 512, 0, stream>>>(
      diff, hB, list, count, WihT, WhhT, b_ih, b_hh, nullptr, nullptr, nullptr);

  // ---- layer 1 ---- (OUT fused in consumer epilogue; gru<LAST> fixes masked)
  fused_layer_kernel<true><<<17 * G, 256, 0, stream>>>(
      hB, offs, csrcol, diff, WdT1, bd + 128, hA, N, nagg, G, flags1,
      Wt, bt, tau_out, list, count + 1, Wo, bo, out_ptr);
  gru_kernel<true><<<gru_blocks, 512, 0, stream>>>(
      diff, hA, list, count + 1, WihT, WhhT, b_ih, b_hh, Wo, bo, out_ptr);
}

// Round 7
// 726.161 us; speedup vs baseline: 8.7238x; 8.7238x over previous
//
#include <hip/hip_runtime.h>
#include <cstdint>
#include <cstddef>

#define HID 128
#define BSHIFT 7            // 128 nodes per bucket -> nbuck = 782 for N=100000
#define NSB 256             // scatter blocks (pass1/pass2 chunking)
#define MAXB 4096           // LDS sort capacity (avg bucket = 2046 edges)

// ROUND-19 NOTES (bit-exactness ledger + schedule ledger):
//  - CONTRACT (R13/R15/R16 fails): h, diff, tau must be BIT-IDENTICAL to the
//    R0 fmaf chains. No dtype compression, no MFMA, no reassociation.
//  - R14: agg needs >=~50% occupancy / small LDS. Keep agg blocks lean.
//  - R5 (PASS 735): role-split agg||gemm-p1 overlap works (~50% of p1
//    absorbed); fp32-partial round-trip is the cost of keeping chains exact.
//  - R6 (PASS bits, 6335us): cross-block flag sync -> per-producer
//    __threadfence() = L2 writeback on non-coherent XCD L2s -> cache thrash,
//    VALUBusy 2.7%. NEVER sync producer->consumer inside a kernel here.
//    R6 DID validate bsort_gin (CSR-sort || input-GEMM role split).
//  - THIS ROUND: R5 schedule verbatim + R6's bsort_gin (validated). All
//    numerics byte-identical to R5-passing code.

// ======== deterministic two-pass bucket scatter (NO global atomics) ========
__global__ __launch_bounds__(256)
void ecount_kernel(const int* __restrict__ row, int* __restrict__ countsT,
                   int E, int nbuck,
                   const float* __restrict__ W_in, const float* __restrict__ Wd,
                   const float* __restrict__ W_ih, const float* __restrict__ W_hh,
                   float* __restrict__ WinT, float* __restrict__ WdT0,
                   float* __restrict__ WdT1, float* __restrict__ WihT,
                   float* __restrict__ WhhT) {
  // --- transpose prelude (180224 elements over 65536 threads) ---
  for (int i = blockIdx.x * 256 + threadIdx.x; i < 180224; i += NSB * 256) {
    int j = i;
    if (j < 16384) { int r = j >> 7, c = j & 127; WinT[c * 128 + r] = W_in[j]; continue; }
    j -= 16384;
    if (j < 32768) { int r = j >> 8, c = j & 255; WdT0[c * 128 + r] = Wd[j]; continue; }
    j -= 32768;
    if (j < 32768) { int r = j >> 8, c = j & 255; WdT1[c * 128 + r] = Wd[32768 + j]; continue; }
    j -= 32768;
    if (j < 49152) { int r = j >> 7, c = j & 127; WihT[c * 384 + r] = W_ih[j]; continue; }
    j -= 49152;
    { int r = j >> 7, c = j & 127; WhhT[c * 384 + r] = W_hh[j]; }
  }
  // --- bucket histogram ---
  __shared__ int lh[1024];
  int b = blockIdx.x;
  for (int i = threadIdx.x; i < nbuck; i += 256) lh[i] = 0;
  __syncthreads();
  int per = (E + NSB - 1) / NSB;
  int s = b * per, e = min(s + per, E);
  for (int i = s + (int)threadIdx.x; i < e; i += 256)
    atomicAdd(&lh[row[i] >> BSHIFT], 1);   // LDS atomic, shallow
  __syncthreads();
  for (int i = threadIdx.x; i < nbuck; i += 256) countsT[i * NSB + b] = lh[i];
}

__global__ __launch_bounds__(NSB)
void bprefix_kernel(int* __restrict__ countsT, int* __restrict__ btotal, int nbuck) {
  __shared__ int sd[NSB];
  int bk = blockIdx.x;
  int t = threadIdx.x;
  int v = countsT[bk * NSB + t];
  sd[t] = v;
  __syncthreads();
  for (int off = 1; off < NSB; off <<= 1) {
    int u = (t >= off) ? sd[t - off] : 0;
    __syncthreads();
    sd[t] += u;
    __syncthreads();
  }
  countsT[bk * NSB + t] = sd[t] - v;       // exclusive within bucket
  if (t == NSB - 1) btotal[bk] = sd[t];
}

__global__ __launch_bounds__(1024)
void bstart_kernel(const int* __restrict__ btotal, int* __restrict__ bstart,
                   int* __restrict__ offsets, int N, int nbuck) {
  __shared__ int sd[1024];
  int t = threadIdx.x;
  int v = (t < nbuck) ? btotal[t] : 0;
  sd[t] = v;
  __syncthreads();
  for (int off = 1; off < 1024; off <<= 1) {
    int u = (t >= off) ? sd[t - off] : 0;
    __syncthreads();
    sd[t] += u;
    __syncthreads();
  }
  if (t < nbuck) bstart[t] = sd[t] - v;
  if (t == nbuck - 1) { bstart[nbuck] = sd[t]; offsets[N] = sd[t]; }
}

__global__ __launch_bounds__(256)
void escatter_kernel(const int* __restrict__ row, const int* __restrict__ col,
                     const int* __restrict__ countsT, const int* __restrict__ bstart,
                     int2* __restrict__ ebuf, int E, int nbuck) {
  __shared__ int lcur[1024];
  int b = blockIdx.x;
  for (int i = threadIdx.x; i < nbuck; i += 256)
    lcur[i] = bstart[i] + countsT[i * NSB + b];
  __syncthreads();
  int per = (E + NSB - 1) / NSB;
  int s = b * per, e = min(s + per, E);
  for (int i = s + (int)threadIdx.x; i < e; i += 256) {
    int r = row[i], c = col[i];
    int pos = atomicAdd(&lcur[r >> BSHIFT], 1);
    ebuf[pos] = make_int2(r, c);
  }
}

// pass 3 + input GEMM (role-split, R6-VALIDATED): bid < nbuck -> per-bucket
// LDS counting sort by row -> CSR (offsets + csrcol), DETERMINISTIC
// (insertion-sorted by col). bid >= nbuck -> gemm_in tile (R5-verbatim):
// hA = relu(x@WinT+b_in). Independent outputs; LDS union'd (25KB); overlaps
// sort (LDS-bound) with gemm (VALU-bound).
__global__ __launch_bounds__(256)
void bsort_gin_kernel(const int2* __restrict__ ebuf, const int* __restrict__ bstart,
                      int* __restrict__ offsets, int* __restrict__ csr_col,
                      int N, int nbuck,
                      const float* __restrict__ A, const float* __restrict__ BT,
                      const float* __restrict__ bias, float* __restrict__ C, int G) {
  __shared__ union {
    struct { int cnt[128]; int off[128]; int cur[128]; int lcol[MAXB]; } s;
    struct { float As[32][68]; float Bs[32][128]; } g;
  } sm;
  int bid = blockIdx.x;
  int tid = threadIdx.x;
  if (bid < nbuck) {
    int bk = bid;
    int s = bstart[bk], e = bstart[bk + 1];
    int m = e - s;
    if (tid < 128) sm.s.cnt[tid] = 0;
    __syncthreads();
    for (int i = s + tid; i < e; i += 256)
      atomicAdd(&sm.s.cnt[ebuf[i].x & 127], 1);
    __syncthreads();
    if (tid < 128) sm.s.off[tid] = sm.s.cnt[tid];
    __syncthreads();
    for (int d = 1; d < 128; d <<= 1) {
      int v = 0;
      if (tid < 128 && tid >= d) v = sm.s.off[tid - d];
      __syncthreads();
      if (tid < 128) sm.s.off[tid] += v;
      __syncthreads();
    }
    if (tid < 128) {
      sm.s.cur[tid] = sm.s.off[tid] - sm.s.cnt[tid];
      int node = (bk << BSHIFT) + tid;
      if (node < N) offsets[node] = s + sm.s.off[tid] - sm.s.cnt[tid];
    }
    __syncthreads();
    if (m <= MAXB) {
      for (int i = s + tid; i < e; i += 256) {
        int2 rc = ebuf[i];
        int pos = atomicAdd(&sm.s.cur[rc.x & 127], 1);
        sm.s.lcol[pos] = rc.y;
      }
      __syncthreads();
      if (tid < 128) {                               // per-node sort by col
        int b0 = sm.s.off[tid] - sm.s.cnt[tid], b1 = sm.s.off[tid];
        for (int i = b0 + 1; i < b1; ++i) {
          int key = sm.s.lcol[i];
          int j = i - 1;
          while (j >= b0 && sm.s.lcol[j] > key) { sm.s.lcol[j + 1] = sm.s.lcol[j]; --j; }
          sm.s.lcol[j + 1] = key;
        }
      }
      __syncthreads();
      for (int i = tid; i < m; i += 256) csr_col[s + i] = sm.s.lcol[i];
    } else {
      // fallback (never expected for this data): unsorted direct scatter
      for (int i = s + tid; i < e; i += 256) {
        int2 rc = ebuf[i];
        int pos = atomicAdd(&sm.s.cur[rc.x & 127], 1);
        csr_col[s + pos] = rc.y;
      }
    }
    return;
  }
  // ---------------- gemm_in tile (R5-verbatim math) ----------------
  int tile = bid - nbuck;
  if (tile >= G) return;
  int tx = tid & 31;
  int ty = tid >> 5;
  int i0 = tile * 64;
  int M = N;
  float acc[8][4] = {};
  for (int kc = 0; kc < 4; ++kc) {
    int ksrc = kc * 32;
    #pragma unroll
    for (int q = 0; q < 2; ++q) {
      int f = q * 256 + tid;
      int i = f >> 3;
      int kq = (f & 7) << 2;
      int ig = i0 + i; if (ig >= M) ig = M - 1;
      float4 v = *(const float4*)(A + (size_t)ig * HID + ksrc + kq);
      sm.g.As[kq + 0][i] = v.x; sm.g.As[kq + 1][i] = v.y;
      sm.g.As[kq + 2][i] = v.z; sm.g.As[kq + 3][i] = v.w;
    }
    #pragma unroll
    for (int q = 0; q < 4; ++q) {
      int f = q * 256 + tid;
      int k = f >> 5; int c4 = (f & 31) << 2;
      *(float4*)&sm.g.Bs[k][c4] = *(const float4*)(BT + (size_t)(ksrc + k) * HID + c4);
    }
    __syncthreads();
    #pragma unroll
    for (int k = 0; k < 32; ++k) {
      float a[8];
      const float4* ap = (const float4*)&sm.g.As[k][ty * 8];
      float4 a0 = ap[0], a1 = ap[1];
      a[0]=a0.x; a[1]=a0.y; a[2]=a0.z; a[3]=a0.w;
      a[4]=a1.x; a[5]=a1.y; a[6]=a1.z; a[7]=a1.w;
      float4 b4 = *(const float4*)&sm.g.Bs[k][tx * 4];
      #pragma unroll
      for (int r = 0; r < 8; ++r) {
        acc[r][0] = fmaf(a[r], b4.x, acc[r][0]);
        acc[r][1] = fmaf(a[r], b4.y, acc[r][1]);
        acc[r][2] = fmaf(a[r], b4.z, acc[r][2]);
        acc[r][3] = fmaf(a[r], b4.w, acc[r][3]);
      }
    }
    __syncthreads();
  }
  float4 bias4 = *(const float4*)(bias + tx * 4);
  #pragma unroll
  for (int r = 0; r < 8; ++r) {
    int row = i0 + ty * 8 + r;
    if (row >= M) continue;
    float4 v4 = make_float4(fmaxf(acc[r][0] + bias4.x, 0.f),
                            fmaxf(acc[r][1] + bias4.y, 0.f),
                            fmaxf(acc[r][2] + bias4.z, 0.f),
                            fmaxf(acc[r][3] + bias4.w, 0.f));
    *(float4*)(C + (size_t)row * HID + tx * 4) = v4;
  }
}

// ---------------- per-node aggregate body (R0-VERBATIM math; frozen) --------
__device__ __forceinline__ void agg_one_node(const float* __restrict__ h,
                                             const int* __restrict__ offsets,
                                             const int* __restrict__ csr_col,
                                             float* __restrict__ diff, int node) {
  int lane = threadIdx.x & 63;
  int start = offsets[node], end = offsets[node + 1];
  int deg = end - start;
  const float2* hrow = (const float2*)(h + (size_t)node * HID);
  float2 hv = hrow[lane];
  float a0 = 0.f, a1 = 0.f;

  int batch = min(deg, 64);
  int myc = (lane < batch) ? csr_col[start + lane] : 0;
  int j = 0;
  for (; j + 16 <= batch; j += 16) {
    const float2* p0 = (const float2*)(h + (size_t)__shfl(myc, j + 0) * HID);
    const float2* p1 = (const float2*)(h + (size_t)__shfl(myc, j + 1) * HID);
    const float2* p2 = (const float2*)(h + (size_t)__shfl(myc, j + 2) * HID);
    const float2* p3 = (const float2*)(h + (size_t)__shfl(myc, j + 3) * HID);
    const float2* p4 = (const float2*)(h + (size_t)__shfl(myc, j + 4) * HID);
    const float2* p5 = (const float2*)(h + (size_t)__shfl(myc, j + 5) * HID);
    const float2* p6 = (const float2*)(h + (size_t)__shfl(myc, j + 6) * HID);
    const float2* p7 = (const float2*)(h + (size_t)__shfl(myc, j + 7) * HID);
    const float2* q0 = (const float2*)(h + (size_t)__shfl(myc, j + 8) * HID);
    const float2* q1 = (const float2*)(h + (size_t)__shfl(myc, j + 9) * HID);
    const float2* q2 = (const float2*)(h + (size_t)__shfl(myc, j + 10) * HID);
    const float2* q3 = (const float2*)(h + (size_t)__shfl(myc, j + 11) * HID);
    const float2* q4 = (const float2*)(h + (size_t)__shfl(myc, j + 12) * HID);
    const float2* q5 = (const float2*)(h + (size_t)__shfl(myc, j + 13) * HID);
    const float2* q6 = (const float2*)(h + (size_t)__shfl(myc, j + 14) * HID);
    const float2* q7 = (const float2*)(h + (size_t)__shfl(myc, j + 15) * HID);
    float2 x0 = p0[lane], x1 = p1[lane], x2 = p2[lane], x3 = p3[lane];
    float2 x4 = p4[lane], x5 = p5[lane], x6 = p6[lane], x7 = p7[lane];
    float2 y0 = q0[lane], y1 = q1[lane], y2 = q2[lane], y3 = q3[lane];
    float2 y4 = q4[lane], y5 = q5[lane], y6 = q6[lane], y7 = q7[lane];
    a0 += fabsf(hv.x - x0.x) + fabsf(hv.x - x1.x) + fabsf(hv.x - x2.x) + fabsf(hv.x - x3.x)
        + fabsf(hv.x - x4.x) + fabsf(hv.x - x5.x) + fabsf(hv.x - x6.x) + fabsf(hv.x - x7.x);
    a1 += fabsf(hv.y - x0.y) + fabsf(hv.y - x1.y) + fabsf(hv.y - x2.y) + fabsf(hv.y - x3.y)
        + fabsf(hv.y - x4.y) + fabsf(hv.y - x5.y) + fabsf(hv.y - x6.y) + fabsf(hv.y - x7.y);
    a0 += fabsf(hv.x - y0.x) + fabsf(hv.x - y1.x) + fabsf(hv.x - y2.x) + fabsf(hv.x - y3.x)
        + fabsf(hv.x - y4.x) + fabsf(hv.x - y5.x) + fabsf(hv.x - y6.x) + fabsf(hv.x - y7.x);
    a1 += fabsf(hv.y - y0.y) + fabsf(hv.y - y1.y) + fabsf(hv.y - y2.y) + fabsf(hv.y - y3.y)
        + fabsf(hv.y - y4.y) + fabsf(hv.y - y5.y) + fabsf(hv.y - y6.y) + fabsf(hv.y - y7.y);
  }
  for (; j + 8 <= batch; j += 8) {
    const float2* p0 = (const float2*)(h + (size_t)__shfl(myc, j + 0) * HID);
    const float2* p1 = (const float2*)(h + (size_t)__shfl(myc, j + 1) * HID);
    const float2* p2 = (const float2*)(h + (size_t)__shfl(myc, j + 2) * HID);
    const float2* p3 = (const float2*)(h + (size_t)__shfl(myc, j + 3) * HID);
    const float2* p4 = (const float2*)(h + (size_t)__shfl(myc, j + 4) * HID);
    const float2* p5 = (const float2*)(h + (size_t)__shfl(myc, j + 5) * HID);
    const float2* p6 = (const float2*)(h + (size_t)__shfl(myc, j + 6) * HID);
    const float2* p7 = (const float2*)(h + (size_t)__shfl(myc, j + 7) * HID);
    float2 x0 = p0[lane], x1 = p1[lane], x2 = p2[lane], x3 = p3[lane];
    float2 x4 = p4[lane], x5 = p5[lane], x6 = p6[lane], x7 = p7[lane];
    a0 += fabsf(hv.x - x0.x) + fabsf(hv.x - x1.x) + fabsf(hv.x - x2.x) + fabsf(hv.x - x3.x)
        + fabsf(hv.x - x4.x) + fabsf(hv.x - x5.x) + fabsf(hv.x - x6.x) + fabsf(hv.x - x7.x);
    a1 += fabsf(hv.y - x0.y) + fabsf(hv.y - x1.y) + fabsf(hv.y - x2.y) + fabsf(hv.y - x3.y)
        + fabsf(hv.y - x4.y) + fabsf(hv.y - x5.y) + fabsf(hv.y - x6.y) + fabsf(hv.y - x7.y);
  }
  for (; j < batch; ++j) {
    const float2* p = (const float2*)(h + (size_t)__shfl(myc, j) * HID);
    float2 x = p[lane];
    a0 += fabsf(hv.x - x.x);
    a1 += fabsf(hv.y - x.y);
  }
  for (int e = start + 64; e < end; ++e) {
    const float2* p = (const float2*)(h + (size_t)csr_col[e] * HID);
    float2 x = p[lane];
    a0 += fabsf(hv.x - x.x);
    a1 += fabsf(hv.y - x.y);
  }
  *(float2*)(diff + (size_t)node * HID + 2 * lane) = make_float2(a0, a1);
}

// ===== kernel1: aggregate ∥ gemm-part1 (role-split, 1:16 interleave) ========
// R5-verbatim (PASSED 735us). gemm blocks (bid%17==0): chunks 0-3 over h,
// fp32 partials to Cpart (layer output buffer, dead). agg blocks: frozen R0
// aggregate, 4 nodes/block. Disjoint writes -> deterministic. NO cross-block
// sync (R6 lesson). LDS 25.6KB + lb(256,4) -> ~50% occ.
__global__ __launch_bounds__(256, 4)
void fused_ap1_kernel(const float* __restrict__ h, const int* __restrict__ offsets,
                      const int* __restrict__ csr_col, float* __restrict__ diff,
                      const float* __restrict__ BT, float* __restrict__ Cpart,
                      int M, int G) {
  __shared__ float As[32][68];
  __shared__ float Bs[32][128];
  int bid = blockIdx.x;
  int tid = threadIdx.x;
  int q17 = bid / 17, r17 = bid % 17;
  if (r17 == 0 && q17 < G) {
    // ---------------- gemm part1: K chunks 0..3 over h ----------------
    int tx = tid & 31;
    int ty = tid >> 5;
    int i0 = q17 * 64;
    float acc[8][4] = {};
    for (int kc = 0; kc < 4; ++kc) {
      int ksrc = kc * 32;
      #pragma unroll
      for (int q = 0; q < 2; ++q) {
        int f = q * 256 + tid;
        int i = f >> 3;
        int kq = (f & 7) << 2;
        int ig = i0 + i; if (ig >= M) ig = M - 1;
        float4 v = *(const float4*)(h + (size_t)ig * HID + ksrc + kq);
        As[kq + 0][i] = v.x; As[kq + 1][i] = v.y;
        As[kq + 2][i] = v.z; As[kq + 3][i] = v.w;
      }
      #pragma unroll
      for (int q = 0; q < 4; ++q) {
        int f = q * 256 + tid;
        int k = f >> 5; int c4 = (f & 31) << 2;
        *(float4*)&Bs[k][c4] = *(const float4*)(BT + (size_t)(ksrc + k) * HID + c4);
      }
      __syncthreads();
      #pragma unroll
      for (int k = 0; k < 32; ++k) {
        float a[8];
        const float4* ap = (const float4*)&As[k][ty * 8];
        float4 a0 = ap[0], a1 = ap[1];
        a[0]=a0.x; a[1]=a0.y; a[2]=a0.z; a[3]=a0.w;
        a[4]=a1.x; a[5]=a1.y; a[6]=a1.z; a[7]=a1.w;
        float4 b4 = *(const float4*)&Bs[k][tx * 4];
        #pragma unroll
        for (int r = 0; r < 8; ++r) {
          acc[r][0] = fmaf(a[r], b4.x, acc[r][0]);
          acc[r][1] = fmaf(a[r], b4.y, acc[r][1]);
          acc[r][2] = fmaf(a[r], b4.z, acc[r][2]);
          acc[r][3] = fmaf(a[r], b4.w, acc[r][3]);
        }
      }
      __syncthreads();
    }
    // store raw fp32 partials (exact round-trip; p2 resumes the chain)
    #pragma unroll
    for (int r = 0; r < 8; ++r) {
      int row = i0 + ty * 8 + r;
      if (row < M) {
        *(float4*)(Cpart + (size_t)row * HID + tx * 4) =
            make_float4(acc[r][0], acc[r][1], acc[r][2], acc[r][3]);
      }
    }
  } else {
    // ---------------- aggregate: 4 nodes (one per wave), R0-frozen ----------
    int ngemm_before = (bid + 16) / 17; if (ngemm_before > G) ngemm_before = G;
    int aidx = bid - ngemm_before;
    int wave = tid >> 6;
    int node = aidx * 4 + wave;
    if (node >= M) return;
    agg_one_node(h, offsets, csr_col, diff, node);
  }
}

// ===== gemm part2: resume chain over diff (chunks 4..7) + R0 epilogue =======
// R5-verbatim (PASSED). Loads fp32 partials from C (same buffer it finalizes;
// per-element same thread -> no hazard). Epilogue: bias/relu/store, tau
// grouping, optional OUT head (masked rows fixed by gru<LAST>).
template<bool OUT>
__global__ __launch_bounds__(256)
void gemm_p2_kernel(const float* __restrict__ A2, const float* __restrict__ BT,
                    const float* __restrict__ bias, float* __restrict__ C,
                    int M,
                    const float* __restrict__ Wt, const float* __restrict__ bt,
                    float* __restrict__ tau_out, int* __restrict__ mlist,
                    int* __restrict__ mcount,
                    const float* __restrict__ Wo, const float* __restrict__ bo,
                    float* __restrict__ outp) {
  __shared__ float As[32][68];
  __shared__ float Bs[32][128];
  __shared__ float taured[64];
  int tid = threadIdx.x;
  int tx = tid & 31;
  int ty = tid >> 5;
  int i0 = blockIdx.x * 64;
  float acc[8][4] = {};
  // reload partials (exact)
  #pragma unroll
  for (int r = 0; r < 8; ++r) {
    int row = i0 + ty * 8 + r;
    if (row < M) {
      float4 v = *(const float4*)(C + (size_t)row * HID + tx * 4);
      acc[r][0] = v.x; acc[r][1] = v.y; acc[r][2] = v.z; acc[r][3] = v.w;
    }
  }
  for (int kc = 4; kc < 8; ++kc) {
    int ksrc = (kc & 3) * 32;
    int kglob = kc * 32;
    #pragma unroll
    for (int q = 0; q < 2; ++q) {
      int f = q * 256 + tid;
      int i = f >> 3;
      int kq = (f & 7) << 2;
      int ig = i0 + i; if (ig >= M) ig = M - 1;
      float4 v = *(const float4*)(A2 + (size_t)ig * HID + ksrc + kq);
      As[kq + 0][i] = v.x; As[kq + 1][i] = v.y;
      As[kq + 2][i] = v.z; As[kq + 3][i] = v.w;
    }
    #pragma unroll
    for (int q = 0; q < 4; ++q) {
      int f = q * 256 + tid;
      int k = f >> 5; int c4 = (f & 31) << 2;
      *(float4*)&Bs[k][c4] = *(const float4*)(BT + (size_t)(kglob + k) * HID + c4);
    }
    __syncthreads();
    #pragma unroll
    for (int k = 0; k < 32; ++k) {
      float a[8];
      const float4* ap = (const float4*)&As[k][ty * 8];
      float4 a0 = ap[0], a1 = ap[1];
      a[0]=a0.x; a[1]=a0.y; a[2]=a0.z; a[3]=a0.w;
      a[4]=a1.x; a[5]=a1.y; a[6]=a1.z; a[7]=a1.w;
      float4 b4 = *(const float4*)&Bs[k][tx * 4];
      #pragma unroll
      for (int r = 0; r < 8; ++r) {
        acc[r][0] = fmaf(a[r], b4.x, acc[r][0]);
        acc[r][1] = fmaf(a[r], b4.y, acc[r][1]);
        acc[r][2] = fmaf(a[r], b4.z, acc[r][2]);
        acc[r][3] = fmaf(a[r], b4.w, acc[r][3]);
      }
    }
    __syncthreads();
  }

  float4 bias4 = *(const float4*)(bias + tx * 4);
  float bias_r[4] = {bias4.x, bias4.y, bias4.z, bias4.w};
  float4 w4 = *(const float4*)(Wt + tx * 4);
  float wt_r[4] = {w4.x, w4.y, w4.z, w4.w};
  float4 wo0 = make_float4(0.f, 0.f, 0.f, 0.f);
  float4 wo1 = make_float4(0.f, 0.f, 0.f, 0.f);
  if constexpr (OUT) {
    wo0 = *(const float4*)(Wo + tx * 4);
    wo1 = *(const float4*)(Wo + 128 + tx * 4);
  }
  #pragma unroll
  for (int r = 0; r < 8; ++r) {
    int row = i0 + ty * 8 + r;
    bool ok = row < M;
    float v0 = fmaxf(acc[r][0] + bias_r[0], 0.f);
    float v1 = fmaxf(acc[r][1] + bias_r[1], 0.f);
    float v2 = fmaxf(acc[r][2] + bias_r[2], 0.f);
    float v3 = fmaxf(acc[r][3] + bias_r[3], 0.f);
    if (ok) {
      float4 v4 = make_float4(v0, v1, v2, v3);
      *(float4*)(C + (size_t)row * HID + tx * 4) = v4;    // dwordx4 store
    }
    if constexpr (OUT) {
      float o0 = v0 * wo0.x + v1 * wo0.y + v2 * wo0.z + v3 * wo0.w;
      float o1 = v0 * wo1.x + v1 * wo1.y + v2 * wo1.z + v3 * wo1.w;
      o0 += __shfl_down(o0, 16, 32); o1 += __shfl_down(o1, 16, 32);
      o0 += __shfl_down(o0, 8, 32);  o1 += __shfl_down(o1, 8, 32);
      o0 += __shfl_down(o0, 4, 32);  o1 += __shfl_down(o1, 4, 32);
      o0 += __shfl_down(o0, 2, 32);  o1 += __shfl_down(o1, 2, 32);
      o0 += __shfl_down(o0, 1, 32);  o1 += __shfl_down(o1, 1, 32);
      if (tx == 0 && ok) {
        outp[(size_t)row * 2 + 0] = o0 + bo[0];
        outp[(size_t)row * 2 + 1] = o1 + bo[1];
      }
    }
    {
      float pf = v0 * wt_r[0];
      pf = fmaf(v1, wt_r[1], pf);
      pf = fmaf(v2, wt_r[2], pf);
      pf = fmaf(v3, wt_r[3], pf);
      pf += __shfl_down(pf, 16, 32);
      pf += __shfl_down(pf, 8, 32);
      pf += __shfl_down(pf, 4, 32);
      pf += __shfl_down(pf, 2, 32);
      pf += __shfl_down(pf, 1, 32);
      if (tx == 0) taured[ty * 8 + r] = pf;
    }
  }
  __syncthreads();
  if (tid < 64) {
    int row = i0 + tid;
    if (row < M) {
      float pre = taured[tid] + bt[0];
      float tau = (pre > 20.f) ? pre : log1pf(expf(pre));
      tau_out[row] = tau;
      // np semantics: floor(1/tau).astype(int32) overflows to INT_MIN for
      // 1/tau >= 2^31 -> n_updates <= 0 -> NOT masked even though tau<0.005.
      if (tau < 0.005f && (1.0f / tau) < 2147483648.0f) {
        int pos = atomicAdd(mcount, 1);
        mlist[pos] = row;
      }
    }
  }
}

// ---------------- masked GRU, 32 nodes / block (512 threads) ----------------
// template<LAST>: LAST recomputes the fused out rows it overwrites (R5-proven).
template<bool LAST>
__global__ __launch_bounds__(512)
void gru_kernel(const float* __restrict__ diff, float* __restrict__ h,
                const int* __restrict__ list, const int* __restrict__ count,
                const float* __restrict__ WihT, const float* __restrict__ WhhT,
                const float* __restrict__ b_ih, const float* __restrict__ b_hh,
                const float* __restrict__ Wo, const float* __restrict__ bo,
                float* __restrict__ outp) {
  int cnt = *count;
  int base = blockIdx.x * 32;
  if (base >= cnt) return;
  __shared__ float dl[32][HID];
  __shared__ float hl[32][HID];
  __shared__ int ids[32];
  __shared__ float osum[32][2][2];   // [row][wave-half][out-dim] (LAST only)
  int tid = threadIdx.x;
  if (tid < 32) ids[tid] = (base + tid < cnt) ? list[base + tid] : -1;
  __syncthreads();
  #pragma unroll
  for (int q = 0; q < 8; ++q) {
    int f = q * 512 + tid;
    int r = f >> 7, c = f & 127;
    int id = ids[r];
    int src = (id >= 0) ? id : 0;
    dl[r][c] = diff[(size_t)src * HID + c];
    hl[r][c] = h[(size_t)src * HID + c];
  }
  __syncthreads();
  int tx = tid & 127, ty = tid >> 7;   // ty in 0..3 -> rows ty*8..ty*8+7
  float air[8] = {}, aiz[8] = {}, ain[8] = {}, ahr[8] = {}, ahz[8] = {}, ahn[8] = {};
  for (int k = 0; k < HID; ++k) {
    float wir = WihT[k * 384 + tx];
    float wiz = WihT[k * 384 + 128 + tx];
    float win = WihT[k * 384 + 256 + tx];
    float whr = WhhT[k * 384 + tx];
    float whz = WhhT[k * 384 + 128 + tx];
    float whn = WhhT[k * 384 + 256 + tx];
    #pragma unroll
    for (int r = 0; r < 8; ++r) {
      float dk = dl[ty * 8 + r][k];
      float hk = hl[ty * 8 + r][k];
      air[r] = fmaf(dk, wir, air[r]);
      aiz[r] = fmaf(dk, wiz, aiz[r]);
      ain[r] = fmaf(dk, win, ain[r]);
      ahr[r] = fmaf(hk, whr, ahr[r]);
      ahz[r] = fmaf(hk, whz, ahz[r]);
      ahn[r] = fmaf(hk, whn, ahn[r]);
    }
  }
  float bir = b_ih[tx], biz = b_ih[128 + tx], bin = b_ih[256 + tx];
  float bhr = b_hh[tx], bhz = b_hh[128 + tx], bhn = b_hh[256 + tx];
  float wol0 = 0.f, wol1 = 0.f;
  if constexpr (LAST) { wol0 = Wo[tx]; wol1 = Wo[128 + tx]; }
  #pragma unroll
  for (int r = 0; r < 8; ++r) {
    int id = ids[ty * 8 + r];
    // compute unconditionally (id<0 rows use row-0 staged data) so the LAST
    // shfl reduce stays non-divergent; only stores are guarded.
    float rg = 1.f / (1.f + expf(-((air[r] + bir) + (ahr[r] + bhr))));
    float z  = 1.f / (1.f + expf(-((aiz[r] + biz) + (ahz[r] + bhz))));
    float n  = tanhf((ain[r] + bin) + rg * (ahn[r] + bhn));
    float hv = hl[ty * 8 + r][tx];
    float hnew = (1.f - z) * n + z * hv;
    if (id >= 0) h[(size_t)id * HID + tx] = hnew;
    if constexpr (LAST) {
      float p0 = hnew * wol0;
      float p1 = hnew * wol1;
      // tx spans 2 waves (0..63 = first, 64..127 = second); 64-lane reduce each
      p0 += __shfl_down(p0, 32, 64); p1 += __shfl_down(p1, 32, 64);
      p0 += __shfl_down(p0, 16, 64); p1 += __shfl_down(p1, 16, 64);
      p0 += __shfl_down(p0, 8, 64);  p1 += __shfl_down(p1, 8, 64);
      p0 += __shfl_down(p0, 4, 64);  p1 += __shfl_down(p1, 4, 64);
      p0 += __shfl_down(p0, 2, 64);  p1 += __shfl_down(p1, 2, 64);
      p0 += __shfl_down(p0, 1, 64);  p1 += __shfl_down(p1, 1, 64);
      if ((tx & 63) == 0) {
        osum[ty * 8 + r][tx >> 6][0] = p0;
        osum[ty * 8 + r][tx >> 6][1] = p1;
      }
    }
  }
  if constexpr (LAST) {
    __syncthreads();
    if (tid < 32) {
      int id = ids[tid];
      if (id >= 0) {
        outp[(size_t)id * 2 + 0] = osum[tid][0][0] + osum[tid][1][0] + bo[0];
        outp[(size_t)id * 2 + 1] = osum[tid][0][1] + osum[tid][1][1] + bo[1];
      }
    }
  }
}

extern "C" void kernel_launch(void* const* d_in, const int* in_sizes, int n_in,
                              void* d_out, int out_size, void* d_ws, size_t ws_size,
                              hipStream_t stream) {
  const float* x    = (const float*)d_in[0];
  const int*   ei   = (const int*)d_in[1];
  const float* W_in = (const float*)d_in[2];
  const float* b_in = (const float*)d_in[3];
  const float* Wd   = (const float*)d_in[4];
  const float* bd   = (const float*)d_in[5];
  const float* Wt   = (const float*)d_in[6];
  const float* bt   = (const float*)d_in[7];
  const float* W_ih = (const float*)d_in[8];
  const float* W_hh = (const float*)d_in[9];
  const float* b_ih = (const float*)d_in[10];
  const float* b_hh = (const float*)d_in[11];
  const float* Wo   = (const float*)d_in[12];
  const float* bo   = (const float*)d_in[13];

  const int N = in_sizes[0] / HID;      // 100000
  const int E = in_sizes[1] / 2;        // 1600000
  const int* rowp = ei;
  const int* colp = ei + E;
  const int nbuck = (N + (1 << BSHIFT) - 1) >> BSHIFT;   // 782 (<=1024)

  // workspace carve-up (256B aligned) — R5 layout
  char* p = (char*)d_ws;
  auto alloc = [&](size_t bytes) { void* r = (void*)p; p += (bytes + 255) & ~(size_t)255; return r; };
  float* hA     = (float*)alloc((size_t)N * HID * 4);
  float* hB     = (float*)alloc((size_t)N * HID * 4);
  float* diff   = (float*)alloc((size_t)N * HID * 4);
  float* WinT   = (float*)alloc(128 * 128 * 4);
  float* WdT0   = (float*)alloc(256 * 128 * 4);
  float* WdT1   = (float*)alloc(256 * 128 * 4);
  float* WihT   = (float*)alloc(128 * 384 * 4);
  float* WhhT   = (float*)alloc(128 * 384 * 4);
  float* tau0   = (float*)alloc((size_t)N * 4);
  int*   list   = (int*)alloc((size_t)N * 4);
  int*   count  = (int*)alloc(256);
  int*   countsT= (int*)alloc((size_t)1024 * NSB * 4);
  int*   btotal = (int*)alloc(1024 * 4);
  int*   bstart = (int*)alloc(1028 * 4);
  int*   offs   = (int*)alloc(((size_t)N + 1) * 4);
  int*   csrcol = (int*)alloc((size_t)E * 4);
  int2*  ebuf   = (int2*)alloc((size_t)E * 8);

  float* out_ptr = (float*)d_out;            // [N,2] flat
  float* tau_out = (float*)d_out + (size_t)N * 2;  // [N]

  // zero both layers' mask counters (ws is poisoned before every launch)
  hipMemsetAsync(count, 0, 8, stream);

  // CSR build, no global atomics, DETERMINISTIC csrcol (reused by both layers)
  ecount_kernel<<<NSB, 256, 0, stream>>>(rowp, countsT, E, nbuck,
                                         W_in, Wd, W_ih, W_hh,
                                         WinT, WdT0, WdT1, WihT, WhhT);
  bprefix_kernel<<<nbuck, NSB, 0, stream>>>(countsT, btotal, nbuck);
  bstart_kernel<<<1, 1024, 0, stream>>>(btotal, bstart, offs, N, nbuck);
  escatter_kernel<<<NSB, 256, 0, stream>>>(rowp, colp, countsT, bstart, ebuf, E, nbuck);

  const int G = (N + 63) / 64;                 // 1563 gemm tiles
  const int agg_groups = (N + 3) / 4;          // 25000 agg blocks (4 nodes ea)
  const int fused_blocks = G + agg_groups;     // 26563, 1:16 interleave
  const int gru_blocks = (N + 31) / 32;

  // bsort + input-layer gemm (role-split, R6-validated): hA = relu(x@WinT+b)
  bsort_gin_kernel<<<nbuck + G, 256, 0, stream>>>(
      ebuf, bstart, offs, csrcol, N, nbuck, x, WinT, b_in, hA, G);

  // ---- layer 0 ----
  fused_ap1_kernel<<<fused_blocks, 256, 0, stream>>>(
      hA, offs, csrcol, diff, WdT0, hB, N, G);
  gemm_p2_kernel<false><<<G, 256, 0, stream>>>(
      diff, WdT0, bd, hB, N, Wt, bt, tau0, list, count,
      nullptr, nullptr, nullptr);
  gru_kernel<false><<<gru_blocks, 512, 0, stream>>>(
      diff, hB, list, count, WihT, WhhT, b_ih, b_hh, nullptr, nullptr, nullptr);

  // ---- layer 1 ---- (OUT fused in p2 epilogue; gru<LAST> fixes masked rows)
  fused_ap1_kernel<<<fused_blocks, 256, 0, stream>>>(
      hB, offs, csrcol, diff, WdT1, hA, N, G);
  gemm_p2_kernel<true><<<G, 256, 0, stream>>>(
      diff, WdT1, bd + 128, hA, N, Wt, bt, tau_out, list, count + 1,
      Wo, bo, out_ptr);
  gru_kernel<true><<<gru_blocks, 512, 0, stream>>>(
      diff, hA, list, count + 1, WihT, WhhT, b_ih, b_hh, Wo, bo, out_ptr);
}

// Round 8
// 654.060 us; speedup vs baseline: 9.6854x; 1.1102x over previous
//
#include <hip/hip_runtime.h>
#include <cstdint>
#include <cstddef>

#define HID 128
#define BSHIFT 7            // 128 nodes per bucket -> nbuck = 782 for N=100000
#define NSB 256             // scatter blocks (pass1/pass2 chunking)
#define MAXB 4096           // LDS sort capacity (avg bucket = 2046 edges)

// ROUND-20 NOTES (bit-exactness ledger + schedule ledger):
//  - CONTRACT (R13/R15/R16 fails): h, diff, tau must be BIT-IDENTICAL to the
//    R0 fmaf chains. No dtype compression, no MFMA, no reassociation.
//  - R14: agg needs >=~50% occupancy / small LDS. Keep agg blocks lean.
//  - R5/R7 (PASS 735/726): role-split agg||gemm-p1 overlap + bsort_gin.
//  - R6 (PASS bits, 6335us): NEVER flag-sync producer->consumer in-kernel
//    (per-producer threadfence = L2 writeback on non-coherent XCD L2s).
//  - THIS ROUND: fuse GRU into gemm_p2's tail. Each p2 block knows its 64
//    rows' masks after its tau epilogue; masked rows (typically 0-2/block)
//    get the VERBATIM gru chains (k-sequential fmaf, same shfl tree for the
//    OUT fixup) using the block's just-stored h row (store->barrier->load,
//    same block) + diff row. Deletes both gru dispatches, the global mask
//    list/count + memset. Block-local mask handling is deterministic (rows
//    independent, writes disjoint).

// ======== deterministic two-pass bucket scatter (NO global atomics) ========
__global__ __launch_bounds__(256)
void ecount_kernel(const int* __restrict__ row, int* __restrict__ countsT,
                   int E, int nbuck,
                   const float* __restrict__ W_in, const float* __restrict__ Wd,
                   const float* __restrict__ W_ih, const float* __restrict__ W_hh,
                   float* __restrict__ WinT, float* __restrict__ WdT0,
                   float* __restrict__ WdT1, float* __restrict__ WihT,
                   float* __restrict__ WhhT) {
  // --- transpose prelude (180224 elements over 65536 threads) ---
  for (int i = blockIdx.x * 256 + threadIdx.x; i < 180224; i += NSB * 256) {
    int j = i;
    if (j < 16384) { int r = j >> 7, c = j & 127; WinT[c * 128 + r] = W_in[j]; continue; }
    j -= 16384;
    if (j < 32768) { int r = j >> 8, c = j & 255; WdT0[c * 128 + r] = Wd[j]; continue; }
    j -= 32768;
    if (j < 32768) { int r = j >> 8, c = j & 255; WdT1[c * 128 + r] = Wd[32768 + j]; continue; }
    j -= 32768;
    if (j < 49152) { int r = j >> 7, c = j & 127; WihT[c * 384 + r] = W_ih[j]; continue; }
    j -= 49152;
    { int r = j >> 7, c = j & 127; WhhT[c * 384 + r] = W_hh[j]; }
  }
  // --- bucket histogram ---
  __shared__ int lh[1024];
  int b = blockIdx.x;
  for (int i = threadIdx.x; i < nbuck; i += 256) lh[i] = 0;
  __syncthreads();
  int per = (E + NSB - 1) / NSB;
  int s = b * per, e = min(s + per, E);
  for (int i = s + (int)threadIdx.x; i < e; i += 256)
    atomicAdd(&lh[row[i] >> BSHIFT], 1);   // LDS atomic, shallow
  __syncthreads();
  for (int i = threadIdx.x; i < nbuck; i += 256) countsT[i * NSB + b] = lh[i];
}

__global__ __launch_bounds__(NSB)
void bprefix_kernel(int* __restrict__ countsT, int* __restrict__ btotal, int nbuck) {
  __shared__ int sd[NSB];
  int bk = blockIdx.x;
  int t = threadIdx.x;
  int v = countsT[bk * NSB + t];
  sd[t] = v;
  __syncthreads();
  for (int off = 1; off < NSB; off <<= 1) {
    int u = (t >= off) ? sd[t - off] : 0;
    __syncthreads();
    sd[t] += u;
    __syncthreads();
  }
  countsT[bk * NSB + t] = sd[t] - v;       // exclusive within bucket
  if (t == NSB - 1) btotal[bk] = sd[t];
}

__global__ __launch_bounds__(1024)
void bstart_kernel(const int* __restrict__ btotal, int* __restrict__ bstart,
                   int* __restrict__ offsets, int N, int nbuck) {
  __shared__ int sd[1024];
  int t = threadIdx.x;
  int v = (t < nbuck) ? btotal[t] : 0;
  sd[t] = v;
  __syncthreads();
  for (int off = 1; off < 1024; off <<= 1) {
    int u = (t >= off) ? sd[t - off] : 0;
    __syncthreads();
    sd[t] += u;
    __syncthreads();
  }
  if (t < nbuck) bstart[t] = sd[t] - v;
  if (t == nbuck - 1) { bstart[nbuck] = sd[t]; offsets[N] = sd[t]; }
}

__global__ __launch_bounds__(256)
void escatter_kernel(const int* __restrict__ row, const int* __restrict__ col,
                     const int* __restrict__ countsT, const int* __restrict__ bstart,
                     int2* __restrict__ ebuf, int E, int nbuck) {
  __shared__ int lcur[1024];
  int b = blockIdx.x;
  for (int i = threadIdx.x; i < nbuck; i += 256)
    lcur[i] = bstart[i] + countsT[i * NSB + b];
  __syncthreads();
  int per = (E + NSB - 1) / NSB;
  int s = b * per, e = min(s + per, E);
  for (int i = s + (int)threadIdx.x; i < e; i += 256) {
    int r = row[i], c = col[i];
    int pos = atomicAdd(&lcur[r >> BSHIFT], 1);
    ebuf[pos] = make_int2(r, c);
  }
}

// pass 3 + input GEMM (role-split, R6/R7-VALIDATED): bid < nbuck -> per-bucket
// LDS counting sort by row -> CSR (offsets + csrcol), DETERMINISTIC
// (insertion-sorted by col). bid >= nbuck -> gemm_in tile (R5-verbatim):
// hA = relu(x@WinT+b_in). Independent outputs; LDS union'd (25KB).
__global__ __launch_bounds__(256)
void bsort_gin_kernel(const int2* __restrict__ ebuf, const int* __restrict__ bstart,
                      int* __restrict__ offsets, int* __restrict__ csr_col,
                      int N, int nbuck,
                      const float* __restrict__ A, const float* __restrict__ BT,
                      const float* __restrict__ bias, float* __restrict__ C, int G) {
  __shared__ union {
    struct { int cnt[128]; int off[128]; int cur[128]; int lcol[MAXB]; } s;
    struct { float As[32][68]; float Bs[32][128]; } g;
  } sm;
  int bid = blockIdx.x;
  int tid = threadIdx.x;
  if (bid < nbuck) {
    int bk = bid;
    int s = bstart[bk], e = bstart[bk + 1];
    int m = e - s;
    if (tid < 128) sm.s.cnt[tid] = 0;
    __syncthreads();
    for (int i = s + tid; i < e; i += 256)
      atomicAdd(&sm.s.cnt[ebuf[i].x & 127], 1);
    __syncthreads();
    if (tid < 128) sm.s.off[tid] = sm.s.cnt[tid];
    __syncthreads();
    for (int d = 1; d < 128; d <<= 1) {
      int v = 0;
      if (tid < 128 && tid >= d) v = sm.s.off[tid - d];
      __syncthreads();
      if (tid < 128) sm.s.off[tid] += v;
      __syncthreads();
    }
    if (tid < 128) {
      sm.s.cur[tid] = sm.s.off[tid] - sm.s.cnt[tid];
      int node = (bk << BSHIFT) + tid;
      if (node < N) offsets[node] = s + sm.s.off[tid] - sm.s.cnt[tid];
    }
    __syncthreads();
    if (m <= MAXB) {
      for (int i = s + tid; i < e; i += 256) {
        int2 rc = ebuf[i];
        int pos = atomicAdd(&sm.s.cur[rc.x & 127], 1);
        sm.s.lcol[pos] = rc.y;
      }
      __syncthreads();
      if (tid < 128) {                               // per-node sort by col
        int b0 = sm.s.off[tid] - sm.s.cnt[tid], b1 = sm.s.off[tid];
        for (int i = b0 + 1; i < b1; ++i) {
          int key = sm.s.lcol[i];
          int j = i - 1;
          while (j >= b0 && sm.s.lcol[j] > key) { sm.s.lcol[j + 1] = sm.s.lcol[j]; --j; }
          sm.s.lcol[j + 1] = key;
        }
      }
      __syncthreads();
      for (int i = tid; i < m; i += 256) csr_col[s + i] = sm.s.lcol[i];
    } else {
      // fallback (never expected for this data): unsorted direct scatter
      for (int i = s + tid; i < e; i += 256) {
        int2 rc = ebuf[i];
        int pos = atomicAdd(&sm.s.cur[rc.x & 127], 1);
        csr_col[s + pos] = rc.y;
      }
    }
    return;
  }
  // ---------------- gemm_in tile (R5-verbatim math) ----------------
  int tile = bid - nbuck;
  if (tile >= G) return;
  int tx = tid & 31;
  int ty = tid >> 5;
  int i0 = tile * 64;
  int M = N;
  float acc[8][4] = {};
  for (int kc = 0; kc < 4; ++kc) {
    int ksrc = kc * 32;
    #pragma unroll
    for (int q = 0; q < 2; ++q) {
      int f = q * 256 + tid;
      int i = f >> 3;
      int kq = (f & 7) << 2;
      int ig = i0 + i; if (ig >= M) ig = M - 1;
      float4 v = *(const float4*)(A + (size_t)ig * HID + ksrc + kq);
      sm.g.As[kq + 0][i] = v.x; sm.g.As[kq + 1][i] = v.y;
      sm.g.As[kq + 2][i] = v.z; sm.g.As[kq + 3][i] = v.w;
    }
    #pragma unroll
    for (int q = 0; q < 4; ++q) {
      int f = q * 256 + tid;
      int k = f >> 5; int c4 = (f & 31) << 2;
      *(float4*)&sm.g.Bs[k][c4] = *(const float4*)(BT + (size_t)(ksrc + k) * HID + c4);
    }
    __syncthreads();
    #pragma unroll
    for (int k = 0; k < 32; ++k) {
      float a[8];
      const float4* ap = (const float4*)&sm.g.As[k][ty * 8];
      float4 a0 = ap[0], a1 = ap[1];
      a[0]=a0.x; a[1]=a0.y; a[2]=a0.z; a[3]=a0.w;
      a[4]=a1.x; a[5]=a1.y; a[6]=a1.z; a[7]=a1.w;
      float4 b4 = *(const float4*)&sm.g.Bs[k][tx * 4];
      #pragma unroll
      for (int r = 0; r < 8; ++r) {
        acc[r][0] = fmaf(a[r], b4.x, acc[r][0]);
        acc[r][1] = fmaf(a[r], b4.y, acc[r][1]);
        acc[r][2] = fmaf(a[r], b4.z, acc[r][2]);
        acc[r][3] = fmaf(a[r], b4.w, acc[r][3]);
      }
    }
    __syncthreads();
  }
  float4 bias4 = *(const float4*)(bias + tx * 4);
  #pragma unroll
  for (int r = 0; r < 8; ++r) {
    int row = i0 + ty * 8 + r;
    if (row >= M) continue;
    float4 v4 = make_float4(fmaxf(acc[r][0] + bias4.x, 0.f),
                            fmaxf(acc[r][1] + bias4.y, 0.f),
                            fmaxf(acc[r][2] + bias4.z, 0.f),
                            fmaxf(acc[r][3] + bias4.w, 0.f));
    *(float4*)(C + (size_t)row * HID + tx * 4) = v4;
  }
}

// ---------------- per-node aggregate body (R0-VERBATIM math; frozen) --------
__device__ __forceinline__ void agg_one_node(const float* __restrict__ h,
                                             const int* __restrict__ offsets,
                                             const int* __restrict__ csr_col,
                                             float* __restrict__ diff, int node) {
  int lane = threadIdx.x & 63;
  int start = offsets[node], end = offsets[node + 1];
  int deg = end - start;
  const float2* hrow = (const float2*)(h + (size_t)node * HID);
  float2 hv = hrow[lane];
  float a0 = 0.f, a1 = 0.f;

  int batch = min(deg, 64);
  int myc = (lane < batch) ? csr_col[start + lane] : 0;
  int j = 0;
  for (; j + 16 <= batch; j += 16) {
    const float2* p0 = (const float2*)(h + (size_t)__shfl(myc, j + 0) * HID);
    const float2* p1 = (const float2*)(h + (size_t)__shfl(myc, j + 1) * HID);
    const float2* p2 = (const float2*)(h + (size_t)__shfl(myc, j + 2) * HID);
    const float2* p3 = (const float2*)(h + (size_t)__shfl(myc, j + 3) * HID);
    const float2* p4 = (const float2*)(h + (size_t)__shfl(myc, j + 4) * HID);
    const float2* p5 = (const float2*)(h + (size_t)__shfl(myc, j + 5) * HID);
    const float2* p6 = (const float2*)(h + (size_t)__shfl(myc, j + 6) * HID);
    const float2* p7 = (const float2*)(h + (size_t)__shfl(myc, j + 7) * HID);
    const float2* q0 = (const float2*)(h + (size_t)__shfl(myc, j + 8) * HID);
    const float2* q1 = (const float2*)(h + (size_t)__shfl(myc, j + 9) * HID);
    const float2* q2 = (const float2*)(h + (size_t)__shfl(myc, j + 10) * HID);
    const float2* q3 = (const float2*)(h + (size_t)__shfl(myc, j + 11) * HID);
    const float2* q4 = (const float2*)(h + (size_t)__shfl(myc, j + 12) * HID);
    const float2* q5 = (const float2*)(h + (size_t)__shfl(myc, j + 13) * HID);
    const float2* q6 = (const float2*)(h + (size_t)__shfl(myc, j + 14) * HID);
    const float2* q7 = (const float2*)(h + (size_t)__shfl(myc, j + 15) * HID);
    float2 x0 = p0[lane], x1 = p1[lane], x2 = p2[lane], x3 = p3[lane];
    float2 x4 = p4[lane], x5 = p5[lane], x6 = p6[lane], x7 = p7[lane];
    float2 y0 = q0[lane], y1 = q1[lane], y2 = q2[lane], y3 = q3[lane];
    float2 y4 = q4[lane], y5 = q5[lane], y6 = q6[lane], y7 = q7[lane];
    a0 += fabsf(hv.x - x0.x) + fabsf(hv.x - x1.x) + fabsf(hv.x - x2.x) + fabsf(hv.x - x3.x)
        + fabsf(hv.x - x4.x) + fabsf(hv.x - x5.x) + fabsf(hv.x - x6.x) + fabsf(hv.x - x7.x);
    a1 += fabsf(hv.y - x0.y) + fabsf(hv.y - x1.y) + fabsf(hv.y - x2.y) + fabsf(hv.y - x3.y)
        + fabsf(hv.y - x4.y) + fabsf(hv.y - x5.y) + fabsf(hv.y - x6.y) + fabsf(hv.y - x7.y);
    a0 += fabsf(hv.x - y0.x) + fabsf(hv.x - y1.x) + fabsf(hv.x - y2.x) + fabsf(hv.x - y3.x)
        + fabsf(hv.x - y4.x) + fabsf(hv.x - y5.x) + fabsf(hv.x - y6.x) + fabsf(hv.x - y7.x);
    a1 += fabsf(hv.y - y0.y) + fabsf(hv.y - y1.y) + fabsf(hv.y - y2.y) + fabsf(hv.y - y3.y)
        + fabsf(hv.y - y4.y) + fabsf(hv.y - y5.y) + fabsf(hv.y - y6.y) + fabsf(hv.y - y7.y);
  }
  for (; j + 8 <= batch; j += 8) {
    const float2* p0 = (const float2*)(h + (size_t)__shfl(myc, j + 0) * HID);
    const float2* p1 = (const float2*)(h + (size_t)__shfl(myc, j + 1) * HID);
    const float2* p2 = (const float2*)(h + (size_t)__shfl(myc, j + 2) * HID);
    const float2* p3 = (const float2*)(h + (size_t)__shfl(myc, j + 3) * HID);
    const float2* p4 = (const float2*)(h + (size_t)__shfl(myc, j + 4) * HID);
    const float2* p5 = (const float2*)(h + (size_t)__shfl(myc, j + 5) * HID);
    const float2* p6 = (const float2*)(h + (size_t)__shfl(myc, j + 6) * HID);
    const float2* p7 = (const float2*)(h + (size_t)__shfl(myc, j + 7) * HID);
    float2 x0 = p0[lane], x1 = p1[lane], x2 = p2[lane], x3 = p3[lane];
    float2 x4 = p4[lane], x5 = p5[lane], x6 = p6[lane], x7 = p7[lane];
    a0 += fabsf(hv.x - x0.x) + fabsf(hv.x - x1.x) + fabsf(hv.x - x2.x) + fabsf(hv.x - x3.x)
        + fabsf(hv.x - x4.x) + fabsf(hv.x - x5.x) + fabsf(hv.x - x6.x) + fabsf(hv.x - x7.x);
    a1 += fabsf(hv.y - x0.y) + fabsf(hv.y - x1.y) + fabsf(hv.y - x2.y) + fabsf(hv.y - x3.y)
        + fabsf(hv.y - x4.y) + fabsf(hv.y - x5.y) + fabsf(hv.y - x6.y) + fabsf(hv.y - x7.y);
  }
  for (; j < batch; ++j) {
    const float2* p = (const float2*)(h + (size_t)__shfl(myc, j) * HID);
    float2 x = p[lane];
    a0 += fabsf(hv.x - x.x);
    a1 += fabsf(hv.y - x.y);
  }
  for (int e = start + 64; e < end; ++e) {
    const float2* p = (const float2*)(h + (size_t)csr_col[e] * HID);
    float2 x = p[lane];
    a0 += fabsf(hv.x - x.x);
    a1 += fabsf(hv.y - x.y);
  }
  *(float2*)(diff + (size_t)node * HID + 2 * lane) = make_float2(a0, a1);
}

// ===== kernel1: aggregate ∥ gemm-part1 (role-split, 1:16 interleave) ========
// R5/R7-verbatim. gemm blocks (bid%17==0): chunks 0-3 over h, fp32 partials
// to Cpart (layer output buffer, dead). agg blocks: frozen R0 aggregate,
// 4 nodes/block. Disjoint writes -> deterministic. NO cross-block sync
// (R6 lesson). LDS 25.6KB + lb(256,4) -> ~50% occ.
__global__ __launch_bounds__(256, 4)
void fused_ap1_kernel(const float* __restrict__ h, const int* __restrict__ offsets,
                      const int* __restrict__ csr_col, float* __restrict__ diff,
                      const float* __restrict__ BT, float* __restrict__ Cpart,
                      int M, int G) {
  __shared__ float As[32][68];
  __shared__ float Bs[32][128];
  int bid = blockIdx.x;
  int tid = threadIdx.x;
  int q17 = bid / 17, r17 = bid % 17;
  if (r17 == 0 && q17 < G) {
    // ---------------- gemm part1: K chunks 0..3 over h ----------------
    int tx = tid & 31;
    int ty = tid >> 5;
    int i0 = q17 * 64;
    float acc[8][4] = {};
    for (int kc = 0; kc < 4; ++kc) {
      int ksrc = kc * 32;
      #pragma unroll
      for (int q = 0; q < 2; ++q) {
        int f = q * 256 + tid;
        int i = f >> 3;
        int kq = (f & 7) << 2;
        int ig = i0 + i; if (ig >= M) ig = M - 1;
        float4 v = *(const float4*)(h + (size_t)ig * HID + ksrc + kq);
        As[kq + 0][i] = v.x; As[kq + 1][i] = v.y;
        As[kq + 2][i] = v.z; As[kq + 3][i] = v.w;
      }
      #pragma unroll
      for (int q = 0; q < 4; ++q) {
        int f = q * 256 + tid;
        int k = f >> 5; int c4 = (f & 31) << 2;
        *(float4*)&Bs[k][c4] = *(const float4*)(BT + (size_t)(ksrc + k) * HID + c4);
      }
      __syncthreads();
      #pragma unroll
      for (int k = 0; k < 32; ++k) {
        float a[8];
        const float4* ap = (const float4*)&As[k][ty * 8];
        float4 a0 = ap[0], a1 = ap[1];
        a[0]=a0.x; a[1]=a0.y; a[2]=a0.z; a[3]=a0.w;
        a[4]=a1.x; a[5]=a1.y; a[6]=a1.z; a[7]=a1.w;
        float4 b4 = *(const float4*)&Bs[k][tx * 4];
        #pragma unroll
        for (int r = 0; r < 8; ++r) {
          acc[r][0] = fmaf(a[r], b4.x, acc[r][0]);
          acc[r][1] = fmaf(a[r], b4.y, acc[r][1]);
          acc[r][2] = fmaf(a[r], b4.z, acc[r][2]);
          acc[r][3] = fmaf(a[r], b4.w, acc[r][3]);
        }
      }
      __syncthreads();
    }
    // store raw fp32 partials (exact round-trip; p2 resumes the chain)
    #pragma unroll
    for (int r = 0; r < 8; ++r) {
      int row = i0 + ty * 8 + r;
      if (row < M) {
        *(float4*)(Cpart + (size_t)row * HID + tx * 4) =
            make_float4(acc[r][0], acc[r][1], acc[r][2], acc[r][3]);
      }
    }
  } else {
    // ---------------- aggregate: 4 nodes (one per wave), R0-frozen ----------
    int ngemm_before = (bid + 16) / 17; if (ngemm_before > G) ngemm_before = G;
    int aidx = bid - ngemm_before;
    int wave = tid >> 6;
    int node = aidx * 4 + wave;
    if (node >= M) return;
    agg_one_node(h, offsets, csr_col, diff, node);
  }
}

// ===== gemm part2 + tau + in-block GRU (+ OUT head) =========================
// R5-verbatim main loop & epilogue. NEW (R20): after tau, masked local rows
// (criterion identical) are collected in LDS and the gru chains run in-block:
// 128 threads per masked row, k-sequential fmaf over staged dl_s/hl_s
// (hl_s re-read from C just stored -> identical values), then for OUT the
// verbatim 64-wide shfl tree + osum combine. Bit-identical to gru_kernel.
template<bool OUT>
__global__ __launch_bounds__(256)
void gemm_p2_kernel(const float* __restrict__ A2, const float* __restrict__ BT,
                    const float* __restrict__ bias, float* __restrict__ C,
                    int M,
                    const float* __restrict__ Wt, const float* __restrict__ bt,
                    float* __restrict__ tau_out,
                    const float* __restrict__ WihT, const float* __restrict__ WhhT,
                    const float* __restrict__ b_ih, const float* __restrict__ b_hh,
                    const float* __restrict__ Wo, const float* __restrict__ bo,
                    float* __restrict__ outp) {
  __shared__ float As[32][68];
  __shared__ float Bs[32][128];
  __shared__ float taured[64];
  __shared__ float dl_s[HID];
  __shared__ float hl_s[HID];
  __shared__ int mrows[64];
  __shared__ int mcnt_s;
  __shared__ float osum_s[2][2];
  int tid = threadIdx.x;
  int tx = tid & 31;
  int ty = tid >> 5;
  int i0 = blockIdx.x * 64;
  if (tid == 0) mcnt_s = 0;
  float acc[8][4] = {};
  // reload partials (exact)
  #pragma unroll
  for (int r = 0; r < 8; ++r) {
    int row = i0 + ty * 8 + r;
    if (row < M) {
      float4 v = *(const float4*)(C + (size_t)row * HID + tx * 4);
      acc[r][0] = v.x; acc[r][1] = v.y; acc[r][2] = v.z; acc[r][3] = v.w;
    }
  }
  for (int kc = 4; kc < 8; ++kc) {
    int ksrc = (kc & 3) * 32;
    int kglob = kc * 32;
    #pragma unroll
    for (int q = 0; q < 2; ++q) {
      int f = q * 256 + tid;
      int i = f >> 3;
      int kq = (f & 7) << 2;
      int ig = i0 + i; if (ig >= M) ig = M - 1;
      float4 v = *(const float4*)(A2 + (size_t)ig * HID + ksrc + kq);
      As[kq + 0][i] = v.x; As[kq + 1][i] = v.y;
      As[kq + 2][i] = v.z; As[kq + 3][i] = v.w;
    }
    #pragma unroll
    for (int q = 0; q < 4; ++q) {
      int f = q * 256 + tid;
      int k = f >> 5; int c4 = (f & 31) << 2;
      *(float4*)&Bs[k][c4] = *(const float4*)(BT + (size_t)(kglob + k) * HID + c4);
    }
    __syncthreads();
    #pragma unroll
    for (int k = 0; k < 32; ++k) {
      float a[8];
      const float4* ap = (const float4*)&As[k][ty * 8];
      float4 a0 = ap[0], a1 = ap[1];
      a[0]=a0.x; a[1]=a0.y; a[2]=a0.z; a[3]=a0.w;
      a[4]=a1.x; a[5]=a1.y; a[6]=a1.z; a[7]=a1.w;
      float4 b4 = *(const float4*)&Bs[k][tx * 4];
      #pragma unroll
      for (int r = 0; r < 8; ++r) {
        acc[r][0] = fmaf(a[r], b4.x, acc[r][0]);
        acc[r][1] = fmaf(a[r], b4.y, acc[r][1]);
        acc[r][2] = fmaf(a[r], b4.z, acc[r][2]);
        acc[r][3] = fmaf(a[r], b4.w, acc[r][3]);
      }
    }
    __syncthreads();
  }

  float4 bias4 = *(const float4*)(bias + tx * 4);
  float bias_r[4] = {bias4.x, bias4.y, bias4.z, bias4.w};
  float4 w4 = *(const float4*)(Wt + tx * 4);
  float wt_r[4] = {w4.x, w4.y, w4.z, w4.w};
  float4 wo0 = make_float4(0.f, 0.f, 0.f, 0.f);
  float4 wo1 = make_float4(0.f, 0.f, 0.f, 0.f);
  if constexpr (OUT) {
    wo0 = *(const float4*)(Wo + tx * 4);
    wo1 = *(const float4*)(Wo + 128 + tx * 4);
  }
  #pragma unroll
  for (int r = 0; r < 8; ++r) {
    int row = i0 + ty * 8 + r;
    bool ok = row < M;
    float v0 = fmaxf(acc[r][0] + bias_r[0], 0.f);
    float v1 = fmaxf(acc[r][1] + bias_r[1], 0.f);
    float v2 = fmaxf(acc[r][2] + bias_r[2], 0.f);
    float v3 = fmaxf(acc[r][3] + bias_r[3], 0.f);
    if (ok) {
      float4 v4 = make_float4(v0, v1, v2, v3);
      *(float4*)(C + (size_t)row * HID + tx * 4) = v4;    // dwordx4 store
    }
    if constexpr (OUT) {
      float o0 = v0 * wo0.x + v1 * wo0.y + v2 * wo0.z + v3 * wo0.w;
      float o1 = v0 * wo1.x + v1 * wo1.y + v2 * wo1.z + v3 * wo1.w;
      o0 += __shfl_down(o0, 16, 32); o1 += __shfl_down(o1, 16, 32);
      o0 += __shfl_down(o0, 8, 32);  o1 += __shfl_down(o1, 8, 32);
      o0 += __shfl_down(o0, 4, 32);  o1 += __shfl_down(o1, 4, 32);
      o0 += __shfl_down(o0, 2, 32);  o1 += __shfl_down(o1, 2, 32);
      o0 += __shfl_down(o0, 1, 32);  o1 += __shfl_down(o1, 1, 32);
      if (tx == 0 && ok) {
        outp[(size_t)row * 2 + 0] = o0 + bo[0];
        outp[(size_t)row * 2 + 1] = o1 + bo[1];
      }
    }
    {
      float pf = v0 * wt_r[0];
      pf = fmaf(v1, wt_r[1], pf);
      pf = fmaf(v2, wt_r[2], pf);
      pf = fmaf(v3, wt_r[3], pf);
      pf += __shfl_down(pf, 16, 32);
      pf += __shfl_down(pf, 8, 32);
      pf += __shfl_down(pf, 4, 32);
      pf += __shfl_down(pf, 2, 32);
      pf += __shfl_down(pf, 1, 32);
      if (tx == 0) taured[ty * 8 + r] = pf;
    }
  }
  __syncthreads();
  if (tid < 64) {
    int row = i0 + tid;
    if (row < M) {
      float pre = taured[tid] + bt[0];
      float tau = (pre > 20.f) ? pre : log1pf(expf(pre));
      tau_out[row] = tau;
      // np semantics: floor(1/tau).astype(int32) overflows to INT_MIN for
      // 1/tau >= 2^31 -> n_updates <= 0 -> NOT masked even though tau<0.005.
      if (tau < 0.005f && (1.0f / tau) < 2147483648.0f) {
        int pos = atomicAdd(&mcnt_s, 1);
        mrows[pos] = tid;                 // local row (order irrelevant)
      }
    }
  }
  __syncthreads();
  int mc = mcnt_s;
  // ---------------- in-block GRU for masked rows (gru_kernel-verbatim) ------
  for (int mi = 0; mi < mc; ++mi) {
    int lrow = mrows[mi];
    int grow = i0 + lrow;
    if (tid < 128) {
      dl_s[tid] = A2[(size_t)grow * HID + tid];          // diff row
      hl_s[tid] = C[(size_t)grow * HID + tid];           // h row (just stored)
    }
    __syncthreads();
    if (tid < 128) {
      int txg = tid;
      float air = 0.f, aiz = 0.f, ain_ = 0.f, ahr = 0.f, ahz = 0.f, ahn = 0.f;
      for (int k = 0; k < HID; ++k) {
        float wir = WihT[k * 384 + txg];
        float wiz = WihT[k * 384 + 128 + txg];
        float win = WihT[k * 384 + 256 + txg];
        float whr = WhhT[k * 384 + txg];
        float whz = WhhT[k * 384 + 128 + txg];
        float whn = WhhT[k * 384 + 256 + txg];
        float dk = dl_s[k];
        float hk = hl_s[k];
        air = fmaf(dk, wir, air);
        aiz = fmaf(dk, wiz, aiz);
        ain_ = fmaf(dk, win, ain_);
        ahr = fmaf(hk, whr, ahr);
        ahz = fmaf(hk, whz, ahz);
        ahn = fmaf(hk, whn, ahn);
      }
      float bir = b_ih[txg], biz = b_ih[128 + txg], bin = b_ih[256 + txg];
      float bhr = b_hh[txg], bhz = b_hh[128 + txg], bhn = b_hh[256 + txg];
      float rg = 1.f / (1.f + expf(-((air + bir) + (ahr + bhr))));
      float z  = 1.f / (1.f + expf(-((aiz + biz) + (ahz + bhz))));
      float n  = tanhf((ain_ + bin) + rg * (ahn + bhn));
      float hv = hl_s[txg];
      float hnew = (1.f - z) * n + z * hv;
      C[(size_t)grow * HID + txg] = hnew;
      if constexpr (OUT) {
        float p0 = hnew * Wo[txg];
        float p1 = hnew * Wo[128 + txg];
        p0 += __shfl_down(p0, 32, 64); p1 += __shfl_down(p1, 32, 64);
        p0 += __shfl_down(p0, 16, 64); p1 += __shfl_down(p1, 16, 64);
        p0 += __shfl_down(p0, 8, 64);  p1 += __shfl_down(p1, 8, 64);
        p0 += __shfl_down(p0, 4, 64);  p1 += __shfl_down(p1, 4, 64);
        p0 += __shfl_down(p0, 2, 64);  p1 += __shfl_down(p1, 2, 64);
        p0 += __shfl_down(p0, 1, 64);  p1 += __shfl_down(p1, 1, 64);
        if ((txg & 63) == 0) {
          osum_s[txg >> 6][0] = p0;
          osum_s[txg >> 6][1] = p1;
        }
      }
    }
    __syncthreads();
    if constexpr (OUT) {
      if (tid == 0) {
        outp[(size_t)grow * 2 + 0] = osum_s[0][0] + osum_s[1][0] + bo[0];
        outp[(size_t)grow * 2 + 1] = osum_s[0][1] + osum_s[1][1] + bo[1];
      }
    }
  }
}

extern "C" void kernel_launch(void* const* d_in, const int* in_sizes, int n_in,
                              void* d_out, int out_size, void* d_ws, size_t ws_size,
                              hipStream_t stream) {
  const float* x    = (const float*)d_in[0];
  const int*   ei   = (const int*)d_in[1];
  const float* W_in = (const float*)d_in[2];
  const float* b_in = (const float*)d_in[3];
  const float* Wd   = (const float*)d_in[4];
  const float* bd   = (const float*)d_in[5];
  const float* Wt   = (const float*)d_in[6];
  const float* bt   = (const float*)d_in[7];
  const float* W_ih = (const float*)d_in[8];
  const float* W_hh = (const float*)d_in[9];
  const float* b_ih = (const float*)d_in[10];
  const float* b_hh = (const float*)d_in[11];
  const float* Wo   = (const float*)d_in[12];
  const float* bo   = (const float*)d_in[13];

  const int N = in_sizes[0] / HID;      // 100000
  const int E = in_sizes[1] / 2;        // 1600000
  const int* rowp = ei;
  const int* colp = ei + E;
  const int nbuck = (N + (1 << BSHIFT) - 1) >> BSHIFT;   // 782 (<=1024)

  // workspace carve-up (256B aligned)
  char* p = (char*)d_ws;
  auto alloc = [&](size_t bytes) { void* r = (void*)p; p += (bytes + 255) & ~(size_t)255; return r; };
  float* hA     = (float*)alloc((size_t)N * HID * 4);
  float* hB     = (float*)alloc((size_t)N * HID * 4);
  float* diff   = (float*)alloc((size_t)N * HID * 4);
  float* WinT   = (float*)alloc(128 * 128 * 4);
  float* WdT0   = (float*)alloc(256 * 128 * 4);
  float* WdT1   = (float*)alloc(256 * 128 * 4);
  float* WihT   = (float*)alloc(128 * 384 * 4);
  float* WhhT   = (float*)alloc(128 * 384 * 4);
  float* tau0   = (float*)alloc((size_t)N * 4);
  int*   countsT= (int*)alloc((size_t)1024 * NSB * 4);
  int*   btotal = (int*)alloc(1024 * 4);
  int*   bstart = (int*)alloc(1028 * 4);
  int*   offs   = (int*)alloc(((size_t)N + 1) * 4);
  int*   csrcol = (int*)alloc((size_t)E * 4);
  int2*  ebuf   = (int2*)alloc((size_t)E * 8);

  float* out_ptr = (float*)d_out;            // [N,2] flat
  float* tau_out = (float*)d_out + (size_t)N * 2;  // [N]

  // CSR build, no global atomics, DETERMINISTIC csrcol (reused by both layers)
  ecount_kernel<<<NSB, 256, 0, stream>>>(rowp, countsT, E, nbuck,
                                         W_in, Wd, W_ih, W_hh,
                                         WinT, WdT0, WdT1, WihT, WhhT);
  bprefix_kernel<<<nbuck, NSB, 0, stream>>>(countsT, btotal, nbuck);
  bstart_kernel<<<1, 1024, 0, stream>>>(btotal, bstart, offs, N, nbuck);
  escatter_kernel<<<NSB, 256, 0, stream>>>(rowp, colp, countsT, bstart, ebuf, E, nbuck);

  const int G = (N + 63) / 64;                 // 1563 gemm tiles
  const int agg_groups = (N + 3) / 4;          // 25000 agg blocks (4 nodes ea)
  const int fused_blocks = G + agg_groups;     // 26563, 1:16 interleave

  // bsort + input-layer gemm (role-split, R6/R7-validated)
  bsort_gin_kernel<<<nbuck + G, 256, 0, stream>>>(
      ebuf, bstart, offs, csrcol, N, nbuck, x, WinT, b_in, hA, G);

  // ---- layer 0 ---- (agg || gemm-p1, then p2 + tau + in-block GRU)
  fused_ap1_kernel<<<fused_blocks, 256, 0, stream>>>(
      hA, offs, csrcol, diff, WdT0, hB, N, G);
  gemm_p2_kernel<false><<<G, 256, 0, stream>>>(
      diff, WdT0, bd, hB, N, Wt, bt, tau0,
      WihT, WhhT, b_ih, b_hh, nullptr, nullptr, nullptr);

  // ---- layer 1 ---- (OUT fused; masked rows' out recomputed in-block)
  fused_ap1_kernel<<<fused_blocks, 256, 0, stream>>>(
      hB, offs, csrcol, diff, WdT1, hA, N, G);
  gemm_p2_kernel<true><<<G, 256, 0, stream>>>(
      diff, WdT1, bd + 128, hA, N, Wt, bt, tau_out,
      WihT, WhhT, b_ih, b_hh, Wo, bo, out_ptr);
}

// Round 9
// 651.652 us; speedup vs baseline: 9.7212x; 1.0037x over previous
//
#include <hip/hip_runtime.h>
#include <cstdint>
#include <cstddef>

#define HID 128
#define BSHIFT 7            // 128 nodes per bucket -> nbuck = 782 for N=100000
#define NSB 256             // scatter blocks (pass1/pass2 chunking)
#define MAXB 4096           // LDS sort capacity (avg bucket = 2046 edges)

// ROUND-21 NOTES (bit-exactness ledger + schedule ledger):
//  - CONTRACT (R13/R15/R16 fails): h, diff, tau must be BIT-IDENTICAL to the
//    R0 fmaf chains. No dtype compression, no MFMA, no reassociation.
//  - R14: agg needs high occupancy / small LDS. R6: NEVER flag-sync
//    producer->consumer in-kernel (threadfence = L2 writeback on
//    non-coherent XCD L2s -> 9x regression).
//  - R5/R7/R8 (PASS 735/726/654): role-split agg||gemm-p1 + bsort_gin +
//    GRU fused into p2 tail. All numeric code frozen-verbatim.
//  - THIS ROUND (zero numeric change): occupancy bump. fused_ap1 ran at
//    42% occ / 3.7 TB/s vs R0 agg's 54% / 3.94 TB/s -> lb(256,4) was the
//    throttle. LDS 25.1KB fits 6 blocks/CU (153.6<=160KB), VGPR 48 << 85
//    cap -> lb(256,6) on fused_ap1 + bsort_gin.

// ======== deterministic two-pass bucket scatter (NO global atomics) ========
__global__ __launch_bounds__(256)
void ecount_kernel(const int* __restrict__ row, int* __restrict__ countsT,
                   int E, int nbuck,
                   const float* __restrict__ W_in, const float* __restrict__ Wd,
                   const float* __restrict__ W_ih, const float* __restrict__ W_hh,
                   float* __restrict__ WinT, float* __restrict__ WdT0,
                   float* __restrict__ WdT1, float* __restrict__ WihT,
                   float* __restrict__ WhhT) {
  // --- transpose prelude (180224 elements over 65536 threads) ---
  for (int i = blockIdx.x * 256 + threadIdx.x; i < 180224; i += NSB * 256) {
    int j = i;
    if (j < 16384) { int r = j >> 7, c = j & 127; WinT[c * 128 + r] = W_in[j]; continue; }
    j -= 16384;
    if (j < 32768) { int r = j >> 8, c = j & 255; WdT0[c * 128 + r] = Wd[j]; continue; }
    j -= 32768;
    if (j < 32768) { int r = j >> 8, c = j & 255; WdT1[c * 128 + r] = Wd[32768 + j]; continue; }
    j -= 32768;
    if (j < 49152) { int r = j >> 7, c = j & 127; WihT[c * 384 + r] = W_ih[j]; continue; }
    j -= 49152;
    { int r = j >> 7, c = j & 127; WhhT[c * 384 + r] = W_hh[j]; }
  }
  // --- bucket histogram ---
  __shared__ int lh[1024];
  int b = blockIdx.x;
  for (int i = threadIdx.x; i < nbuck; i += 256) lh[i] = 0;
  __syncthreads();
  int per = (E + NSB - 1) / NSB;
  int s = b * per, e = min(s + per, E);
  for (int i = s + (int)threadIdx.x; i < e; i += 256)
    atomicAdd(&lh[row[i] >> BSHIFT], 1);   // LDS atomic, shallow
  __syncthreads();
  for (int i = threadIdx.x; i < nbuck; i += 256) countsT[i * NSB + b] = lh[i];
}

__global__ __launch_bounds__(NSB)
void bprefix_kernel(int* __restrict__ countsT, int* __restrict__ btotal, int nbuck) {
  __shared__ int sd[NSB];
  int bk = blockIdx.x;
  int t = threadIdx.x;
  int v = countsT[bk * NSB + t];
  sd[t] = v;
  __syncthreads();
  for (int off = 1; off < NSB; off <<= 1) {
    int u = (t >= off) ? sd[t - off] : 0;
    __syncthreads();
    sd[t] += u;
    __syncthreads();
  }
  countsT[bk * NSB + t] = sd[t] - v;       // exclusive within bucket
  if (t == NSB - 1) btotal[bk] = sd[t];
}

__global__ __launch_bounds__(1024)
void bstart_kernel(const int* __restrict__ btotal, int* __restrict__ bstart,
                   int* __restrict__ offsets, int N, int nbuck) {
  __shared__ int sd[1024];
  int t = threadIdx.x;
  int v = (t < nbuck) ? btotal[t] : 0;
  sd[t] = v;
  __syncthreads();
  for (int off = 1; off < 1024; off <<= 1) {
    int u = (t >= off) ? sd[t - off] : 0;
    __syncthreads();
    sd[t] += u;
    __syncthreads();
  }
  if (t < nbuck) bstart[t] = sd[t] - v;
  if (t == nbuck - 1) { bstart[nbuck] = sd[t]; offsets[N] = sd[t]; }
}

__global__ __launch_bounds__(256)
void escatter_kernel(const int* __restrict__ row, const int* __restrict__ col,
                     const int* __restrict__ countsT, const int* __restrict__ bstart,
                     int2* __restrict__ ebuf, int E, int nbuck) {
  __shared__ int lcur[1024];
  int b = blockIdx.x;
  for (int i = threadIdx.x; i < nbuck; i += 256)
    lcur[i] = bstart[i] + countsT[i * NSB + b];
  __syncthreads();
  int per = (E + NSB - 1) / NSB;
  int s = b * per, e = min(s + per, E);
  for (int i = s + (int)threadIdx.x; i < e; i += 256) {
    int r = row[i], c = col[i];
    int pos = atomicAdd(&lcur[r >> BSHIFT], 1);
    ebuf[pos] = make_int2(r, c);
  }
}

// pass 3 + input GEMM (role-split, R6/R7-VALIDATED): bid < nbuck -> per-bucket
// LDS counting sort by row -> CSR (offsets + csrcol), DETERMINISTIC
// (insertion-sorted by col). bid >= nbuck -> gemm_in tile (R5-verbatim):
// hA = relu(x@WinT+b_in). Independent outputs; LDS union'd (25KB).
__global__ __launch_bounds__(256, 6)
void bsort_gin_kernel(const int2* __restrict__ ebuf, const int* __restrict__ bstart,
                      int* __restrict__ offsets, int* __restrict__ csr_col,
                      int N, int nbuck,
                      const float* __restrict__ A, const float* __restrict__ BT,
                      const float* __restrict__ bias, float* __restrict__ C, int G) {
  __shared__ union {
    struct { int cnt[128]; int off[128]; int cur[128]; int lcol[MAXB]; } s;
    struct { float As[32][68]; float Bs[32][128]; } g;
  } sm;
  int bid = blockIdx.x;
  int tid = threadIdx.x;
  if (bid < nbuck) {
    int bk = bid;
    int s = bstart[bk], e = bstart[bk + 1];
    int m = e - s;
    if (tid < 128) sm.s.cnt[tid] = 0;
    __syncthreads();
    for (int i = s + tid; i < e; i += 256)
      atomicAdd(&sm.s.cnt[ebuf[i].x & 127], 1);
    __syncthreads();
    if (tid < 128) sm.s.off[tid] = sm.s.cnt[tid];
    __syncthreads();
    for (int d = 1; d < 128; d <<= 1) {
      int v = 0;
      if (tid < 128 && tid >= d) v = sm.s.off[tid - d];
      __syncthreads();
      if (tid < 128) sm.s.off[tid] += v;
      __syncthreads();
    }
    if (tid < 128) {
      sm.s.cur[tid] = sm.s.off[tid] - sm.s.cnt[tid];
      int node = (bk << BSHIFT) + tid;
      if (node < N) offsets[node] = s + sm.s.off[tid] - sm.s.cnt[tid];
    }
    __syncthreads();
    if (m <= MAXB) {
      for (int i = s + tid; i < e; i += 256) {
        int2 rc = ebuf[i];
        int pos = atomicAdd(&sm.s.cur[rc.x & 127], 1);
        sm.s.lcol[pos] = rc.y;
      }
      __syncthreads();
      if (tid < 128) {                               // per-node sort by col
        int b0 = sm.s.off[tid] - sm.s.cnt[tid], b1 = sm.s.off[tid];
        for (int i = b0 + 1; i < b1; ++i) {
          int key = sm.s.lcol[i];
          int j = i - 1;
          while (j >= b0 && sm.s.lcol[j] > key) { sm.s.lcol[j + 1] = sm.s.lcol[j]; --j; }
          sm.s.lcol[j + 1] = key;
        }
      }
      __syncthreads();
      for (int i = tid; i < m; i += 256) csr_col[s + i] = sm.s.lcol[i];
    } else {
      // fallback (never expected for this data): unsorted direct scatter
      for (int i = s + tid; i < e; i += 256) {
        int2 rc = ebuf[i];
        int pos = atomicAdd(&sm.s.cur[rc.x & 127], 1);
        csr_col[s + pos] = rc.y;
      }
    }
    return;
  }
  // ---------------- gemm_in tile (R5-verbatim math) ----------------
  int tile = bid - nbuck;
  if (tile >= G) return;
  int tx = tid & 31;
  int ty = tid >> 5;
  int i0 = tile * 64;
  int M = N;
  float acc[8][4] = {};
  for (int kc = 0; kc < 4; ++kc) {
    int ksrc = kc * 32;
    #pragma unroll
    for (int q = 0; q < 2; ++q) {
      int f = q * 256 + tid;
      int i = f >> 3;
      int kq = (f & 7) << 2;
      int ig = i0 + i; if (ig >= M) ig = M - 1;
      float4 v = *(const float4*)(A + (size_t)ig * HID + ksrc + kq);
      sm.g.As[kq + 0][i] = v.x; sm.g.As[kq + 1][i] = v.y;
      sm.g.As[kq + 2][i] = v.z; sm.g.As[kq + 3][i] = v.w;
    }
    #pragma unroll
    for (int q = 0; q < 4; ++q) {
      int f = q * 256 + tid;
      int k = f >> 5; int c4 = (f & 31) << 2;
      *(float4*)&sm.g.Bs[k][c4] = *(const float4*)(BT + (size_t)(ksrc + k) * HID + c4);
    }
    __syncthreads();
    #pragma unroll
    for (int k = 0; k < 32; ++k) {
      float a[8];
      const float4* ap = (const float4*)&sm.g.As[k][ty * 8];
      float4 a0 = ap[0], a1 = ap[1];
      a[0]=a0.x; a[1]=a0.y; a[2]=a0.z; a[3]=a0.w;
      a[4]=a1.x; a[5]=a1.y; a[6]=a1.z; a[7]=a1.w;
      float4 b4 = *(const float4*)&sm.g.Bs[k][tx * 4];
      #pragma unroll
      for (int r = 0; r < 8; ++r) {
        acc[r][0] = fmaf(a[r], b4.x, acc[r][0]);
        acc[r][1] = fmaf(a[r], b4.y, acc[r][1]);
        acc[r][2] = fmaf(a[r], b4.z, acc[r][2]);
        acc[r][3] = fmaf(a[r], b4.w, acc[r][3]);
      }
    }
    __syncthreads();
  }
  float4 bias4 = *(const float4*)(bias + tx * 4);
  #pragma unroll
  for (int r = 0; r < 8; ++r) {
    int row = i0 + ty * 8 + r;
    if (row >= M) continue;
    float4 v4 = make_float4(fmaxf(acc[r][0] + bias4.x, 0.f),
                            fmaxf(acc[r][1] + bias4.y, 0.f),
                            fmaxf(acc[r][2] + bias4.z, 0.f),
                            fmaxf(acc[r][3] + bias4.w, 0.f));
    *(float4*)(C + (size_t)row * HID + tx * 4) = v4;
  }
}

// ---------------- per-node aggregate body (R0-VERBATIM math; frozen) --------
__device__ __forceinline__ void agg_one_node(const float* __restrict__ h,
                                             const int* __restrict__ offsets,
                                             const int* __restrict__ csr_col,
                                             float* __restrict__ diff, int node) {
  int lane = threadIdx.x & 63;
  int start = offsets[node], end = offsets[node + 1];
  int deg = end - start;
  const float2* hrow = (const float2*)(h + (size_t)node * HID);
  float2 hv = hrow[lane];
  float a0 = 0.f, a1 = 0.f;

  int batch = min(deg, 64);
  int myc = (lane < batch) ? csr_col[start + lane] : 0;
  int j = 0;
  for (; j + 16 <= batch; j += 16) {
    const float2* p0 = (const float2*)(h + (size_t)__shfl(myc, j + 0) * HID);
    const float2* p1 = (const float2*)(h + (size_t)__shfl(myc, j + 1) * HID);
    const float2* p2 = (const float2*)(h + (size_t)__shfl(myc, j + 2) * HID);
    const float2* p3 = (const float2*)(h + (size_t)__shfl(myc, j + 3) * HID);
    const float2* p4 = (const float2*)(h + (size_t)__shfl(myc, j + 4) * HID);
    const float2* p5 = (const float2*)(h + (size_t)__shfl(myc, j + 5) * HID);
    const float2* p6 = (const float2*)(h + (size_t)__shfl(myc, j + 6) * HID);
    const float2* p7 = (const float2*)(h + (size_t)__shfl(myc, j + 7) * HID);
    const float2* q0 = (const float2*)(h + (size_t)__shfl(myc, j + 8) * HID);
    const float2* q1 = (const float2*)(h + (size_t)__shfl(myc, j + 9) * HID);
    const float2* q2 = (const float2*)(h + (size_t)__shfl(myc, j + 10) * HID);
    const float2* q3 = (const float2*)(h + (size_t)__shfl(myc, j + 11) * HID);
    const float2* q4 = (const float2*)(h + (size_t)__shfl(myc, j + 12) * HID);
    const float2* q5 = (const float2*)(h + (size_t)__shfl(myc, j + 13) * HID);
    const float2* q6 = (const float2*)(h + (size_t)__shfl(myc, j + 14) * HID);
    const float2* q7 = (const float2*)(h + (size_t)__shfl(myc, j + 15) * HID);
    float2 x0 = p0[lane], x1 = p1[lane], x2 = p2[lane], x3 = p3[lane];
    float2 x4 = p4[lane], x5 = p5[lane], x6 = p6[lane], x7 = p7[lane];
    float2 y0 = q0[lane], y1 = q1[lane], y2 = q2[lane], y3 = q3[lane];
    float2 y4 = q4[lane], y5 = q5[lane], y6 = q6[lane], y7 = q7[lane];
    a0 += fabsf(hv.x - x0.x) + fabsf(hv.x - x1.x) + fabsf(hv.x - x2.x) + fabsf(hv.x - x3.x)
        + fabsf(hv.x - x4.x) + fabsf(hv.x - x5.x) + fabsf(hv.x - x6.x) + fabsf(hv.x - x7.x);
    a1 += fabsf(hv.y - x0.y) + fabsf(hv.y - x1.y) + fabsf(hv.y - x2.y) + fabsf(hv.y - x3.y)
        + fabsf(hv.y - x4.y) + fabsf(hv.y - x5.y) + fabsf(hv.y - x6.y) + fabsf(hv.y - x7.y);
    a0 += fabsf(hv.x - y0.x) + fabsf(hv.x - y1.x) + fabsf(hv.x - y2.x) + fabsf(hv.x - y3.x)
        + fabsf(hv.x - y4.x) + fabsf(hv.x - y5.x) + fabsf(hv.x - y6.x) + fabsf(hv.x - y7.x);
    a1 += fabsf(hv.y - y0.y) + fabsf(hv.y - y1.y) + fabsf(hv.y - y2.y) + fabsf(hv.y - y3.y)
        + fabsf(hv.y - y4.y) + fabsf(hv.y - y5.y) + fabsf(hv.y - y6.y) + fabsf(hv.y - y7.y);
  }
  for (; j + 8 <= batch; j += 8) {
    const float2* p0 = (const float2*)(h + (size_t)__shfl(myc, j + 0) * HID);
    const float2* p1 = (const float2*)(h + (size_t)__shfl(myc, j + 1) * HID);
    const float2* p2 = (const float2*)(h + (size_t)__shfl(myc, j + 2) * HID);
    const float2* p3 = (const float2*)(h + (size_t)__shfl(myc, j + 3) * HID);
    const float2* p4 = (const float2*)(h + (size_t)__shfl(myc, j + 4) * HID);
    const float2* p5 = (const float2*)(h + (size_t)__shfl(myc, j + 5) * HID);
    const float2* p6 = (const float2*)(h + (size_t)__shfl(myc, j + 6) * HID);
    const float2* p7 = (const float2*)(h + (size_t)__shfl(myc, j + 7) * HID);
    float2 x0 = p0[lane], x1 = p1[lane], x2 = p2[lane], x3 = p3[lane];
    float2 x4 = p4[lane], x5 = p5[lane], x6 = p6[lane], x7 = p7[lane];
    a0 += fabsf(hv.x - x0.x) + fabsf(hv.x - x1.x) + fabsf(hv.x - x2.x) + fabsf(hv.x - x3.x)
        + fabsf(hv.x - x4.x) + fabsf(hv.x - x5.x) + fabsf(hv.x - x6.x) + fabsf(hv.x - x7.x);
    a1 += fabsf(hv.y - x0.y) + fabsf(hv.y - x1.y) + fabsf(hv.y - x2.y) + fabsf(hv.y - x3.y)
        + fabsf(hv.y - x4.y) + fabsf(hv.y - x5.y) + fabsf(hv.y - x6.y) + fabsf(hv.y - x7.y);
  }
  for (; j < batch; ++j) {
    const float2* p = (const float2*)(h + (size_t)__shfl(myc, j) * HID);
    float2 x = p[lane];
    a0 += fabsf(hv.x - x.x);
    a1 += fabsf(hv.y - x.y);
  }
  for (int e = start + 64; e < end; ++e) {
    const float2* p = (const float2*)(h + (size_t)csr_col[e] * HID);
    float2 x = p[lane];
    a0 += fabsf(hv.x - x.x);
    a1 += fabsf(hv.y - x.y);
  }
  *(float2*)(diff + (size_t)node * HID + 2 * lane) = make_float2(a0, a1);
}

// ===== kernel1: aggregate ∥ gemm-part1 (role-split, 1:16 interleave) ========
// R5/R7-verbatim math. gemm blocks (bid%17==0): chunks 0-3 over h, fp32
// partials to Cpart (layer output buffer, dead). agg blocks: frozen R0
// aggregate, 4 nodes/block. Disjoint writes -> deterministic. NO cross-block
// sync (R6 lesson). R21: lb(256,6) — LDS 25.6KB fits 6 blocks/CU, VGPR 48
// << 85 cap; raises occupancy ceiling 50%->75% for more outstanding gathers.
__global__ __launch_bounds__(256, 6)
void fused_ap1_kernel(const float* __restrict__ h, const int* __restrict__ offsets,
                      const int* __restrict__ csr_col, float* __restrict__ diff,
                      const float* __restrict__ BT, float* __restrict__ Cpart,
                      int M, int G) {
  __shared__ float As[32][68];
  __shared__ float Bs[32][128];
  int bid = blockIdx.x;
  int tid = threadIdx.x;
  int q17 = bid / 17, r17 = bid % 17;
  if (r17 == 0 && q17 < G) {
    // ---------------- gemm part1: K chunks 0..3 over h ----------------
    int tx = tid & 31;
    int ty = tid >> 5;
    int i0 = q17 * 64;
    float acc[8][4] = {};
    for (int kc = 0; kc < 4; ++kc) {
      int ksrc = kc * 32;
      #pragma unroll
      for (int q = 0; q < 2; ++q) {
        int f = q * 256 + tid;
        int i = f >> 3;
        int kq = (f & 7) << 2;
        int ig = i0 + i; if (ig >= M) ig = M - 1;
        float4 v = *(const float4*)(h + (size_t)ig * HID + ksrc + kq);
        As[kq + 0][i] = v.x; As[kq + 1][i] = v.y;
        As[kq + 2][i] = v.z; As[kq + 3][i] = v.w;
      }
      #pragma unroll
      for (int q = 0; q < 4; ++q) {
        int f = q * 256 + tid;
        int k = f >> 5; int c4 = (f & 31) << 2;
        *(float4*)&Bs[k][c4] = *(const float4*)(BT + (size_t)(ksrc + k) * HID + c4);
      }
      __syncthreads();
      #pragma unroll
      for (int k = 0; k < 32; ++k) {
        float a[8];
        const float4* ap = (const float4*)&As[k][ty * 8];
        float4 a0 = ap[0], a1 = ap[1];
        a[0]=a0.x; a[1]=a0.y; a[2]=a0.z; a[3]=a0.w;
        a[4]=a1.x; a[5]=a1.y; a[6]=a1.z; a[7]=a1.w;
        float4 b4 = *(const float4*)&Bs[k][tx * 4];
        #pragma unroll
        for (int r = 0; r < 8; ++r) {
          acc[r][0] = fmaf(a[r], b4.x, acc[r][0]);
          acc[r][1] = fmaf(a[r], b4.y, acc[r][1]);
          acc[r][2] = fmaf(a[r], b4.z, acc[r][2]);
          acc[r][3] = fmaf(a[r], b4.w, acc[r][3]);
        }
      }
      __syncthreads();
    }
    // store raw fp32 partials (exact round-trip; p2 resumes the chain)
    #pragma unroll
    for (int r = 0; r < 8; ++r) {
      int row = i0 + ty * 8 + r;
      if (row < M) {
        *(float4*)(Cpart + (size_t)row * HID + tx * 4) =
            make_float4(acc[r][0], acc[r][1], acc[r][2], acc[r][3]);
      }
    }
  } else {
    // ---------------- aggregate: 4 nodes (one per wave), R0-frozen ----------
    int ngemm_before = (bid + 16) / 17; if (ngemm_before > G) ngemm_before = G;
    int aidx = bid - ngemm_before;
    int wave = tid >> 6;
    int node = aidx * 4 + wave;
    if (node >= M) return;
    agg_one_node(h, offsets, csr_col, diff, node);
  }
}

// ===== gemm part2 + tau + in-block GRU (+ OUT head) =========================
// R8-verbatim (PASSED 654). Main loop & epilogue R5-verbatim; masked local
// rows get the gru chains in-block (bit-identical to old gru_kernel).
template<bool OUT>
__global__ __launch_bounds__(256)
void gemm_p2_kernel(const float* __restrict__ A2, const float* __restrict__ BT,
                    const float* __restrict__ bias, float* __restrict__ C,
                    int M,
                    const float* __restrict__ Wt, const float* __restrict__ bt,
                    float* __restrict__ tau_out,
                    const float* __restrict__ WihT, const float* __restrict__ WhhT,
                    const float* __restrict__ b_ih, const float* __restrict__ b_hh,
                    const float* __restrict__ Wo, const float* __restrict__ bo,
                    float* __restrict__ outp) {
  __shared__ float As[32][68];
  __shared__ float Bs[32][128];
  __shared__ float taured[64];
  __shared__ float dl_s[HID];
  __shared__ float hl_s[HID];
  __shared__ int mrows[64];
  __shared__ int mcnt_s;
  __shared__ float osum_s[2][2];
  int tid = threadIdx.x;
  int tx = tid & 31;
  int ty = tid >> 5;
  int i0 = blockIdx.x * 64;
  if (tid == 0) mcnt_s = 0;
  float acc[8][4] = {};
  // reload partials (exact)
  #pragma unroll
  for (int r = 0; r < 8; ++r) {
    int row = i0 + ty * 8 + r;
    if (row < M) {
      float4 v = *(const float4*)(C + (size_t)row * HID + tx * 4);
      acc[r][0] = v.x; acc[r][1] = v.y; acc[r][2] = v.z; acc[r][3] = v.w;
    }
  }
  for (int kc = 4; kc < 8; ++kc) {
    int ksrc = (kc & 3) * 32;
    int kglob = kc * 32;
    #pragma unroll
    for (int q = 0; q < 2; ++q) {
      int f = q * 256 + tid;
      int i = f >> 3;
      int kq = (f & 7) << 2;
      int ig = i0 + i; if (ig >= M) ig = M - 1;
      float4 v = *(const float4*)(A2 + (size_t)ig * HID + ksrc + kq);
      As[kq + 0][i] = v.x; As[kq + 1][i] = v.y;
      As[kq + 2][i] = v.z; As[kq + 3][i] = v.w;
    }
    #pragma unroll
    for (int q = 0; q < 4; ++q) {
      int f = q * 256 + tid;
      int k = f >> 5; int c4 = (f & 31) << 2;
      *(float4*)&Bs[k][c4] = *(const float4*)(BT + (size_t)(kglob + k) * HID + c4);
    }
    __syncthreads();
    #pragma unroll
    for (int k = 0; k < 32; ++k) {
      float a[8];
      const float4* ap = (const float4*)&As[k][ty * 8];
      float4 a0 = ap[0], a1 = ap[1];
      a[0]=a0.x; a[1]=a0.y; a[2]=a0.z; a[3]=a0.w;
      a[4]=a1.x; a[5]=a1.y; a[6]=a1.z; a[7]=a1.w;
      float4 b4 = *(const float4*)&Bs[k][tx * 4];
      #pragma unroll
      for (int r = 0; r < 8; ++r) {
        acc[r][0] = fmaf(a[r], b4.x, acc[r][0]);
        acc[r][1] = fmaf(a[r], b4.y, acc[r][1]);
        acc[r][2] = fmaf(a[r], b4.z, acc[r][2]);
        acc[r][3] = fmaf(a[r], b4.w, acc[r][3]);
      }
    }
    __syncthreads();
  }

  float4 bias4 = *(const float4*)(bias + tx * 4);
  float bias_r[4] = {bias4.x, bias4.y, bias4.z, bias4.w};
  float4 w4 = *(const float4*)(Wt + tx * 4);
  float wt_r[4] = {w4.x, w4.y, w4.z, w4.w};
  float4 wo0 = make_float4(0.f, 0.f, 0.f, 0.f);
  float4 wo1 = make_float4(0.f, 0.f, 0.f, 0.f);
  if constexpr (OUT) {
    wo0 = *(const float4*)(Wo + tx * 4);
    wo1 = *(const float4*)(Wo + 128 + tx * 4);
  }
  #pragma unroll
  for (int r = 0; r < 8; ++r) {
    int row = i0 + ty * 8 + r;
    bool ok = row < M;
    float v0 = fmaxf(acc[r][0] + bias_r[0], 0.f);
    float v1 = fmaxf(acc[r][1] + bias_r[1], 0.f);
    float v2 = fmaxf(acc[r][2] + bias_r[2], 0.f);
    float v3 = fmaxf(acc[r][3] + bias_r[3], 0.f);
    if (ok) {
      float4 v4 = make_float4(v0, v1, v2, v3);
      *(float4*)(C + (size_t)row * HID + tx * 4) = v4;    // dwordx4 store
    }
    if constexpr (OUT) {
      float o0 = v0 * wo0.x + v1 * wo0.y + v2 * wo0.z + v3 * wo0.w;
      float o1 = v0 * wo1.x + v1 * wo1.y + v2 * wo1.z + v3 * wo1.w;
      o0 += __shfl_down(o0, 16, 32); o1 += __shfl_down(o1, 16, 32);
      o0 += __shfl_down(o0, 8, 32);  o1 += __shfl_down(o1, 8, 32);
      o0 += __shfl_down(o0, 4, 32);  o1 += __shfl_down(o1, 4, 32);
      o0 += __shfl_down(o0, 2, 32);  o1 += __shfl_down(o1, 2, 32);
      o0 += __shfl_down(o0, 1, 32);  o1 += __shfl_down(o1, 1, 32);
      if (tx == 0 && ok) {
        outp[(size_t)row * 2 + 0] = o0 + bo[0];
        outp[(size_t)row * 2 + 1] = o1 + bo[1];
      }
    }
    {
      float pf = v0 * wt_r[0];
      pf = fmaf(v1, wt_r[1], pf);
      pf = fmaf(v2, wt_r[2], pf);
      pf = fmaf(v3, wt_r[3], pf);
      pf += __shfl_down(pf, 16, 32);
      pf += __shfl_down(pf, 8, 32);
      pf += __shfl_down(pf, 4, 32);
      pf += __shfl_down(pf, 2, 32);
      pf += __shfl_down(pf, 1, 32);
      if (tx == 0) taured[ty * 8 + r] = pf;
    }
  }
  __syncthreads();
  if (tid < 64) {
    int row = i0 + tid;
    if (row < M) {
      float pre = taured[tid] + bt[0];
      float tau = (pre > 20.f) ? pre : log1pf(expf(pre));
      tau_out[row] = tau;
      // np semantics: floor(1/tau).astype(int32) overflows to INT_MIN for
      // 1/tau >= 2^31 -> n_updates <= 0 -> NOT masked even though tau<0.005.
      if (tau < 0.005f && (1.0f / tau) < 2147483648.0f) {
        int pos = atomicAdd(&mcnt_s, 1);
        mrows[pos] = tid;                 // local row (order irrelevant)
      }
    }
  }
  __syncthreads();
  int mc = mcnt_s;
  // ---------------- in-block GRU for masked rows (gru_kernel-verbatim) ------
  for (int mi = 0; mi < mc; ++mi) {
    int lrow = mrows[mi];
    int grow = i0 + lrow;
    if (tid < 128) {
      dl_s[tid] = A2[(size_t)grow * HID + tid];          // diff row
      hl_s[tid] = C[(size_t)grow * HID + tid];           // h row (just stored)
    }
    __syncthreads();
    if (tid < 128) {
      int txg = tid;
      float air = 0.f, aiz = 0.f, ain_ = 0.f, ahr = 0.f, ahz = 0.f, ahn = 0.f;
      for (int k = 0; k < HID; ++k) {
        float wir = WihT[k * 384 + txg];
        float wiz = WihT[k * 384 + 128 + txg];
        float win = WihT[k * 384 + 256 + txg];
        float whr = WhhT[k * 384 + txg];
        float whz = WhhT[k * 384 + 128 + txg];
        float whn = WhhT[k * 384 + 256 + txg];
        float dk = dl_s[k];
        float hk = hl_s[k];
        air = fmaf(dk, wir, air);
        aiz = fmaf(dk, wiz, aiz);
        ain_ = fmaf(dk, win, ain_);
        ahr = fmaf(hk, whr, ahr);
        ahz = fmaf(hk, whz, ahz);
        ahn = fmaf(hk, whn, ahn);
      }
      float bir = b_ih[txg], biz = b_ih[128 + txg], bin = b_ih[256 + txg];
      float bhr = b_hh[txg], bhz = b_hh[128 + txg], bhn = b_hh[256 + txg];
      float rg = 1.f / (1.f + expf(-((air + bir) + (ahr + bhr))));
      float z  = 1.f / (1.f + expf(-((aiz + biz) + (ahz + bhz))));
      float n  = tanhf((ain_ + bin) + rg * (ahn + bhn));
      float hv = hl_s[txg];
      float hnew = (1.f - z) * n + z * hv;
      C[(size_t)grow * HID + txg] = hnew;
      if constexpr (OUT) {
        float p0 = hnew * Wo[txg];
        float p1 = hnew * Wo[128 + txg];
        p0 += __shfl_down(p0, 32, 64); p1 += __shfl_down(p1, 32, 64);
        p0 += __shfl_down(p0, 16, 64); p1 += __shfl_down(p1, 16, 64);
        p0 += __shfl_down(p0, 8, 64);  p1 += __shfl_down(p1, 8, 64);
        p0 += __shfl_down(p0, 4, 64);  p1 += __shfl_down(p1, 4, 64);
        p0 += __shfl_down(p0, 2, 64);  p1 += __shfl_down(p1, 2, 64);
        p0 += __shfl_down(p0, 1, 64);  p1 += __shfl_down(p1, 1, 64);
        if ((txg & 63) == 0) {
          osum_s[txg >> 6][0] = p0;
          osum_s[txg >> 6][1] = p1;
        }
      }
    }
    __syncthreads();
    if constexpr (OUT) {
      if (tid == 0) {
        outp[(size_t)grow * 2 + 0] = osum_s[0][0] + osum_s[1][0] + bo[0];
        outp[(size_t)grow * 2 + 1] = osum_s[0][1] + osum_s[1][1] + bo[1];
      }
    }
  }
}

extern "C" void kernel_launch(void* const* d_in, const int* in_sizes, int n_in,
                              void* d_out, int out_size, void* d_ws, size_t ws_size,
                              hipStream_t stream) {
  const float* x    = (const float*)d_in[0];
  const int*   ei   = (const int*)d_in[1];
  const float* W_in = (const float*)d_in[2];
  const float* b_in = (const float*)d_in[3];
  const float* Wd   = (const float*)d_in[4];
  const float* bd   = (const float*)d_in[5];
  const float* Wt   = (const float*)d_in[6];
  const float* bt   = (const float*)d_in[7];
  const float* W_ih = (const float*)d_in[8];
  const float* W_hh = (const float*)d_in[9];
  const float* b_ih = (const float*)d_in[10];
  const float* b_hh = (const float*)d_in[11];
  const float* Wo   = (const float*)d_in[12];
  const float* bo   = (const float*)d_in[13];

  const int N = in_sizes[0] / HID;      // 100000
  const int E = in_sizes[1] / 2;        // 1600000
  const int* rowp = ei;
  const int* colp = ei + E;
  const int nbuck = (N + (1 << BSHIFT) - 1) >> BSHIFT;   // 782 (<=1024)

  // workspace carve-up (256B aligned)
  char* p = (char*)d_ws;
  auto alloc = [&](size_t bytes) { void* r = (void*)p; p += (bytes + 255) & ~(size_t)255; return r; };
  float* hA     = (float*)alloc((size_t)N * HID * 4);
  float* hB     = (float*)alloc((size_t)N * HID * 4);
  float* diff   = (float*)alloc((size_t)N * HID * 4);
  float* WinT   = (float*)alloc(128 * 128 * 4);
  float* WdT0   = (float*)alloc(256 * 128 * 4);
  float* WdT1   = (float*)alloc(256 * 128 * 4);
  float* WihT   = (float*)alloc(128 * 384 * 4);
  float* WhhT   = (float*)alloc(128 * 384 * 4);
  float* tau0   = (float*)alloc((size_t)N * 4);
  int*   countsT= (int*)alloc((size_t)1024 * NSB * 4);
  int*   btotal = (int*)alloc(1024 * 4);
  int*   bstart = (int*)alloc(1028 * 4);
  int*   offs   = (int*)alloc(((size_t)N + 1) * 4);
  int*   csrcol = (int*)alloc((size_t)E * 4);
  int2*  ebuf   = (int2*)alloc((size_t)E * 8);

  float* out_ptr = (float*)d_out;            // [N,2] flat
  float* tau_out = (float*)d_out + (size_t)N * 2;  // [N]

  // CSR build, no global atomics, DETERMINISTIC csrcol (reused by both layers)
  ecount_kernel<<<NSB, 256, 0, stream>>>(rowp, countsT, E, nbuck,
                                         W_in, Wd, W_ih, W_hh,
                                         WinT, WdT0, WdT1, WihT, WhhT);
  bprefix_kernel<<<nbuck, NSB, 0, stream>>>(countsT, btotal, nbuck);
  bstart_kernel<<<1, 1024, 0, stream>>>(btotal, bstart, offs, N, nbuck);
  escatter_kernel<<<NSB, 256, 0, stream>>>(rowp, colp, countsT, bstart, ebuf, E, nbuck);

  const int G = (N + 63) / 64;                 // 1563 gemm tiles
  const int agg_groups = (N + 3) / 4;          // 25000 agg blocks (4 nodes ea)
  const int fused_blocks = G + agg_groups;     // 26563, 1:16 interleave

  // bsort + input-layer gemm (role-split, R6/R7-validated)
  bsort_gin_kernel<<<nbuck + G, 256, 0, stream>>>(
      ebuf, bstart, offs, csrcol, N, nbuck, x, WinT, b_in, hA, G);

  // ---- layer 0 ---- (agg || gemm-p1, then p2 + tau + in-block GRU)
  fused_ap1_kernel<<<fused_blocks, 256, 0, stream>>>(
      hA, offs, csrcol, diff, WdT0, hB, N, G);
  gemm_p2_kernel<false><<<G, 256, 0, stream>>>(
      diff, WdT0, bd, hB, N, Wt, bt, tau0,
      WihT, WhhT, b_ih, b_hh, nullptr, nullptr, nullptr);

  // ---- layer 1 ---- (OUT fused; masked rows' out recomputed in-block)
  fused_ap1_kernel<<<fused_blocks, 256, 0, stream>>>(
      hB, offs, csrcol, diff, WdT1, hA, N, G);
  gemm_p2_kernel<true><<<G, 256, 0, stream>>>(
      diff, WdT1, bd + 128, hA, N, Wt, bt, tau_out,
      WihT, WhhT, b_ih, b_hh, Wo, bo, out_ptr);
}